// Round 2
// baseline (7800.724 us; speedup 1.0000x reference)
//
#include <hip/hip_runtime.h>
#include <hip/hip_bf16.h>
#include <stdint.h>

typedef unsigned short ushort_t;
typedef short short8 __attribute__((ext_vector_type(8)));
typedef unsigned short ushortx8 __attribute__((ext_vector_type(8)));
typedef float floatx4 __attribute__((ext_vector_type(4)));

__device__ __forceinline__ float b2f(ushort_t u) {
    return __uint_as_float(((unsigned int)u) << 16);
}
__device__ __forceinline__ ushort_t f2bf(float f) {
    unsigned int u = __float_as_uint(f);
    unsigned int r = u + 0x7FFFu + ((u >> 16) & 1u);
    return (ushort_t)(r >> 16);
}

// ---------------- transpose + downcast: out_bf16[n*K + k] = in_f32[k*N + n], batched ----
__global__ void transpose_kernel(const float* __restrict__ in, ushort_t* __restrict__ out,
                                 int K, int N) {
    __shared__ float tile[32][33];
    in += (long)blockIdx.z * K * N;
    out += (long)blockIdx.z * K * N;
    int k0 = blockIdx.x * 32, n0 = blockIdx.y * 32;
    int x = threadIdx.x, y = threadIdx.y;  // (32, 8)
#pragma unroll
    for (int i = 0; i < 4; i++)
        tile[y + 8 * i][x] = in[(long)(k0 + y + 8 * i) * N + n0 + x];
    __syncthreads();
#pragma unroll
    for (int i = 0; i < 4; i++)
        out[(long)(n0 + y + 8 * i) * K + k0 + x] = f2bf(tile[x][y + 8 * i]);
}

// ---------------- LayerNorm over C=1024, f32 in -> bf16 out ----------------
__global__ __launch_bounds__(256) void ln_kernel(const float* __restrict__ in,
                                                 ushort_t* __restrict__ out,
                                                 const float* __restrict__ g,
                                                 const float* __restrict__ b) {
    long row = blockIdx.x;
    int tid = threadIdx.x;
    float4 v4 = *((const float4*)(in + row * 1024) + tid);
    float v[4] = {v4.x, v4.y, v4.z, v4.w};
    float s1 = v[0] + v[1] + v[2] + v[3];
    float s2 = v[0] * v[0] + v[1] * v[1] + v[2] * v[2] + v[3] * v[3];
#pragma unroll
    for (int m = 32; m >= 1; m >>= 1) {
        s1 += __shfl_xor(s1, m);
        s2 += __shfl_xor(s2, m);
    }
    __shared__ float r1[4], r2[4];
    int w = tid >> 6;
    if ((tid & 63) == 0) { r1[w] = s1; r2[w] = s2; }
    __syncthreads();
    s1 = r1[0] + r1[1] + r1[2] + r1[3];
    s2 = r2[0] + r2[1] + r2[2] + r2[3];
    float mu = s1 * (1.0f / 1024.0f);
    float var = s2 * (1.0f / 1024.0f) - mu * mu;
    float inv = rsqrtf(var + 1e-5f);
    float y[4];
#pragma unroll
    for (int i = 0; i < 4; i++)
        y[i] = (v[i] - mu) * inv * g[tid * 4 + i] + b[tid * 4 + i];
    unsigned int lo = (unsigned int)f2bf(y[0]) | ((unsigned int)f2bf(y[1]) << 16);
    unsigned int hi = (unsigned int)f2bf(y[2]) | ((unsigned int)f2bf(y[3]) << 16);
    *(uint2*)(out + row * 1024 + tid * 4) = make_uint2(lo, hi);
}

// ---------------- generic 64x64 MFMA GEMM tile, bf16 A and B^T, fp32 acc ----------------
// C[m][n] = act( sum_k A[m][k]*Bt[n][k] + bias[n] ) (+ resid)
// C/resid addressing: off = (m>>11)*cBatch + (m&2047)*ldc + n
template <typename OutT, int RELU>
__device__ __forceinline__ void gemm_core(
    const ushort_t* __restrict__ A, int lda,
    const ushort_t* __restrict__ Bt, int ldb, int K,
    OutT* __restrict__ C, long cBatch, int ldc,
    const float* __restrict__ bias,
    const float* __restrict__ resid,
    int m0, int n0, ushort_t* As, ushort_t* Bs) {
    int tid = threadIdx.x;
    int lane = tid & 63, w = tid >> 6;
    int ln = lane & 15, quad = lane >> 4;
    int srow = tid >> 2, scol = (tid & 3) * 8;

    floatx4 acc[4] = {{0, 0, 0, 0}, {0, 0, 0, 0}, {0, 0, 0, 0}, {0, 0, 0, 0}};

    const ushort_t* gA = A + (long)(m0 + srow) * lda + scol;
    const ushort_t* gB = Bt + (long)(n0 + srow) * ldb + scol;
    ushort_t* sA = As + srow * 40 + scol;
    ushort_t* sB = Bs + srow * 40 + scol;

    for (int k0 = 0; k0 < K; k0 += 32) {
        __syncthreads();
        *(int4*)sA = *(const int4*)(gA + k0);
        *(int4*)sB = *(const int4*)(gB + k0);
        __syncthreads();
        short8 af = *(const short8*)(As + (w * 16 + ln) * 40 + quad * 8);
#pragma unroll
        for (int j = 0; j < 4; j++) {
            short8 bf = *(const short8*)(Bs + (j * 16 + ln) * 40 + quad * 8);
            acc[j] = __builtin_amdgcn_mfma_f32_16x16x32_bf16(af, bf, acc[j], 0, 0, 0);
        }
    }
#pragma unroll
    for (int j = 0; j < 4; j++) {
        int gn = n0 + j * 16 + ln;
        float bv = bias ? bias[gn] : 0.0f;
#pragma unroll
        for (int r = 0; r < 4; r++) {
            int gm = m0 + w * 16 + quad * 4 + r;
            long off = (long)(gm >> 11) * cBatch + (long)(gm & 2047) * ldc + gn;
            float val = acc[j][r] + bv;
            if (RELU) val = fmaxf(val, 0.0f);
            if (resid) val += resid[off];
            if constexpr (sizeof(OutT) == 2)
                C[off] = (OutT)f2bf(val);
            else
                C[off] = (OutT)val;
        }
    }
}

__global__ __launch_bounds__(256) void gemm_f32out_kernel(
    const ushort_t* __restrict__ A, int lda,
    const ushort_t* __restrict__ Bt, int ldb, int K,
    float* __restrict__ C, long cBatch, int ldc,
    const float* __restrict__ bias, const float* __restrict__ resid) {
    __shared__ ushort_t As[64 * 40];
    __shared__ ushort_t Bs[64 * 40];
    gemm_core<float, 0>(A, lda, Bt, ldb, K, C, cBatch, ldc, bias, resid,
                        blockIdx.x * 64, blockIdx.y * 64, As, Bs);
}

__global__ __launch_bounds__(256) void gemm_bf16out_relu_kernel(
    const ushort_t* __restrict__ A, int lda,
    const ushort_t* __restrict__ Bt, int ldb, int K,
    ushort_t* __restrict__ C, long cBatch, int ldc,
    const float* __restrict__ bias) {
    __shared__ ushort_t As[64 * 40];
    __shared__ ushort_t Bs[64 * 40];
    gemm_core<ushort_t, 1>(A, lda, Bt, ldb, K, C, cBatch, ldc, bias, nullptr,
                           blockIdx.x * 64, blockIdx.y * 64, As, Bs);
}

// QKV: z = mat*16 + h; writes q/k/v in [B,H,T,DH] bf16
__global__ __launch_bounds__(256) void gemm_qkv_kernel(
    const ushort_t* __restrict__ xn,
    const ushort_t* __restrict__ WqT, const ushort_t* __restrict__ WkT,
    const ushort_t* __restrict__ WvT,
    const float* __restrict__ bq, const float* __restrict__ bk,
    const float* __restrict__ bv,
    ushort_t* __restrict__ qb, ushort_t* __restrict__ kb, ushort_t* __restrict__ vb) {
    __shared__ ushort_t As[64 * 40];
    __shared__ ushort_t Bs[64 * 40];
    int z = blockIdx.z;
    int mat = z >> 4, h = z & 15;
    const ushort_t* Bt = (mat == 0 ? WqT : mat == 1 ? WkT : WvT) + (long)h * 64 * 1024;
    const float* bias = (mat == 0 ? bq : mat == 1 ? bk : bv) + h * 64;
    ushort_t* C = (mat == 0 ? qb : mat == 1 ? kb : vb) + (long)h * 2048 * 64;
    gemm_core<ushort_t, 0>(xn, 1024, Bt, 1024, 1024, C, (long)16 * 2048 * 64, 64,
                           bias, nullptr, blockIdx.x * 64, 0, As, Bs);
}

// ---------------- attention: scores = (q.k)*8, softmax, o = p.v (vector ALU) -------------
// one 32-lane group per query row; 8 rows per block of 256
__global__ __launch_bounds__(256) void attn_kernel(
    const ushort_t* __restrict__ q, const ushort_t* __restrict__ k,
    const ushort_t* __restrict__ v, ushort_t* __restrict__ o) {
    int b = blockIdx.z, h = blockIdx.y;
    int t0 = blockIdx.x * 8;
    int tid = threadIdx.x;
    int r = tid >> 5, u = tid & 31;
    long bh = ((long)b * 16 + h) * 2048;
    const ushort_t* qrow = q + (bh + t0 + r) * 64;
    float qv[64];
#pragma unroll
    for (int i = 0; i < 8; i++) {
        ushortx8 t = *(const ushortx8*)(qrow + i * 8);
#pragma unroll
        for (int j = 0; j < 8; j++) qv[i * 8 + j] = b2f(t[j]) * 8.0f;  // fold * sqrt(DH)
    }
    const ushort_t* kbase = k + bh * 64;
    const ushort_t* vbase = v + bh * 64;
    float sc[64];
#pragma unroll
    for (int si = 0; si < 64; si++) {
        const ushort_t* krow = kbase + (long)(u + si * 32) * 64;
        float acc = 0.0f;
#pragma unroll
        for (int i = 0; i < 8; i++) {
            ushortx8 t = *(const ushortx8*)(krow + i * 8);
#pragma unroll
            for (int j = 0; j < 8; j++) acc += qv[i * 8 + j] * b2f(t[j]);
        }
        sc[si] = acc;
    }
    float mx = -1e30f;
#pragma unroll
    for (int si = 0; si < 64; si++) mx = fmaxf(mx, sc[si]);
#pragma unroll
    for (int m = 16; m >= 1; m >>= 1) mx = fmaxf(mx, __shfl_xor(mx, m));
    float sum = 0.0f;
#pragma unroll
    for (int si = 0; si < 64; si++) {
        sc[si] = __expf(sc[si] - mx);
        sum += sc[si];
    }
#pragma unroll
    for (int m = 16; m >= 1; m >>= 1) sum += __shfl_xor(sum, m);
    float inv = 1.0f / sum;
    float op[64];
#pragma unroll
    for (int d = 0; d < 64; d++) op[d] = 0.0f;
#pragma unroll
    for (int si = 0; si < 64; si++) {
        const ushort_t* vrow = vbase + (long)(u + si * 32) * 64;
        float p = sc[si];
#pragma unroll
        for (int i = 0; i < 8; i++) {
            ushortx8 t = *(const ushortx8*)(vrow + i * 8);
#pragma unroll
            for (int j = 0; j < 8; j++) op[i * 8 + j] += p * b2f(t[j]);
        }
    }
#pragma unroll
    for (int m = 1; m <= 16; m <<= 1) {
#pragma unroll
        for (int d = 0; d < 64; d++) op[d] += __shfl_xor(op[d], m);
    }
    // concat-head layout: o[b][t][h*64+d]
    ushort_t* orow = o + ((long)b * 2048 + t0 + r) * 1024 + h * 64;
#pragma unroll
    for (int d = 0; d < 64; d++) {
        if (u == (d & 31)) orow[d] = f2bf(op[d] * inv);
    }
}

extern "C" void kernel_launch(void* const* d_in, const int* in_sizes, int n_in,
                              void* d_out, int out_size, void* d_ws, size_t ws_size,
                              hipStream_t stream) {
    const float* x   = (const float*)d_in[0];
    const float* Wq  = (const float*)d_in[1];
    const float* bq  = (const float*)d_in[2];
    const float* Wk  = (const float*)d_in[3];
    const float* bk  = (const float*)d_in[4];
    const float* Wv  = (const float*)d_in[5];
    const float* bv  = (const float*)d_in[6];
    const float* Wo  = (const float*)d_in[7];
    const float* bo  = (const float*)d_in[8];
    const float* g1  = (const float*)d_in[9];
    const float* be1 = (const float*)d_in[10];
    const float* g2  = (const float*)d_in[11];
    const float* be2 = (const float*)d_in[12];
    const float* W1  = (const float*)d_in[13];
    const float* b1  = (const float*)d_in[14];
    const float* W2  = (const float*)d_in[15];
    const float* b2  = (const float*)d_in[16];
    float* out = (float*)d_out;

    const long MB = 1 << 20;
    char* w = (char*)d_ws;
    ushort_t* xn  = (ushort_t*)(w);            // [8192,1024] bf16; reused as attn output o
    float*    x2  = (float*)(w + 16 * MB);     // [8192,1024] f32
    ushort_t* qb  = (ushort_t*)(w + 48 * MB);  // [B,H,T,DH] bf16
    ushort_t* kb  = (ushort_t*)(w + 64 * MB);
    ushort_t* vb  = (ushort_t*)(w + 80 * MB);
    ushort_t* xn2 = qb;                        // alias (qb dead after attention)
    ushort_t* h1  = (ushort_t*)(w + 64 * MB);  // [8192,2048] bf16 (kb/vb dead)
    ushort_t* WqT = (ushort_t*)(w + 96 * MB);  // [H,DH,C]
    ushort_t* WkT = (ushort_t*)(w + 98 * MB);
    ushort_t* WvT = (ushort_t*)(w + 100 * MB);
    ushort_t* WoT = (ushort_t*)(w + 102 * MB); // [C,C]^T
    ushort_t* W1T = (ushort_t*)(w + 104 * MB); // [DFF,C]
    ushort_t* W2T = (ushort_t*)(w + 112 * MB); // [C,DFF]  (ends at 120 MB)

    dim3 tb(32, 8);
    transpose_kernel<<<dim3(32, 2, 16), tb, 0, stream>>>(Wq, WqT, 1024, 64);
    transpose_kernel<<<dim3(32, 2, 16), tb, 0, stream>>>(Wk, WkT, 1024, 64);
    transpose_kernel<<<dim3(32, 2, 16), tb, 0, stream>>>(Wv, WvT, 1024, 64);
    transpose_kernel<<<dim3(32, 32, 1), tb, 0, stream>>>(Wo, WoT, 1024, 1024);
    transpose_kernel<<<dim3(32, 128, 1), tb, 0, stream>>>(W1, W1T, 1024, 4096);
    transpose_kernel<<<dim3(128, 32, 1), tb, 0, stream>>>(W2, W2T, 4096, 1024);

    ln_kernel<<<8192, 256, 0, stream>>>(x, xn, g1, be1);
    gemm_qkv_kernel<<<dim3(128, 1, 48), 256, 0, stream>>>(xn, WqT, WkT, WvT, bq, bk, bv,
                                                          qb, kb, vb);
    attn_kernel<<<dim3(256, 16, 4), 256, 0, stream>>>(qb, kb, vb, xn /* o */);
    // x2 = x + o @ Wo + bo   (fp32 out)
    gemm_f32out_kernel<<<dim3(128, 16), 256, 0, stream>>>(xn, 1024, WoT, 1024, 1024,
                                                          x2, 2048L * 1024, 1024, bo, x);
    ln_kernel<<<8192, 256, 0, stream>>>((const float*)x2, xn2, g2, be2);
    // FFN in two DFF=2048 halves to keep ws under 120 MB
    // h1 = relu(xn2 @ W1T[0:2048] + b1[0:2048]); out = x2 + h1 @ W2T[:, k 0:2048] + b2
    gemm_bf16out_relu_kernel<<<dim3(128, 32), 256, 0, stream>>>(
        xn2, 1024, W1T, 1024, 1024, h1, 2048L * 2048, 2048, b1);
    gemm_f32out_kernel<<<dim3(128, 16), 256, 0, stream>>>(
        h1, 2048, W2T, 4096, 2048, out, 2048L * 1024, 1024, b2, x2);
    // second half accumulates into out (resid = out, no bias)
    gemm_bf16out_relu_kernel<<<dim3(128, 32), 256, 0, stream>>>(
        xn2, 1024, W1T + 2048L * 1024, 1024, 1024, h1, 2048L * 2048, 2048, b1 + 2048);
    gemm_f32out_kernel<<<dim3(128, 16), 256, 0, stream>>>(
        h1, 2048, W2T + 2048, 4096, 2048, out, 2048L * 1024, 1024, nullptr, out);
}

// Round 3
// 884.854 us; speedup vs baseline: 8.8158x; 8.8158x over previous
//
#include <hip/hip_runtime.h>
#include <hip/hip_bf16.h>
#include <stdint.h>

typedef unsigned short ushort_t;
typedef short short8 __attribute__((ext_vector_type(8)));
typedef unsigned short ushortx8 __attribute__((ext_vector_type(8)));
typedef float floatx4 __attribute__((ext_vector_type(4)));

__device__ __forceinline__ float b2f(ushort_t u) {
    return __uint_as_float(((unsigned int)u) << 16);
}
__device__ __forceinline__ ushort_t f2bf(float f) {
    unsigned int u = __float_as_uint(f);
    unsigned int r = u + 0x7FFFu + ((u >> 16) & 1u);
    return (ushort_t)(r >> 16);
}

// ---------------- transpose + downcast: out_bf16[n*K + k] = in_f32[k*N + n], batched ----
__global__ void transpose_kernel(const float* __restrict__ in, ushort_t* __restrict__ out,
                                 int K, int N) {
    __shared__ float tile[32][33];
    in += (long)blockIdx.z * K * N;
    out += (long)blockIdx.z * K * N;
    int k0 = blockIdx.x * 32, n0 = blockIdx.y * 32;
    int x = threadIdx.x, y = threadIdx.y;  // (32, 8)
#pragma unroll
    for (int i = 0; i < 4; i++)
        tile[y + 8 * i][x] = in[(long)(k0 + y + 8 * i) * N + n0 + x];
    __syncthreads();
#pragma unroll
    for (int i = 0; i < 4; i++)
        out[(long)(n0 + y + 8 * i) * K + k0 + x] = f2bf(tile[x][y + 8 * i]);
}

// ---------------- LayerNorm over C=1024, f32 in -> bf16 out ----------------
__global__ __launch_bounds__(256) void ln_kernel(const float* __restrict__ in,
                                                 ushort_t* __restrict__ out,
                                                 const float* __restrict__ g,
                                                 const float* __restrict__ b) {
    long row = blockIdx.x;
    int tid = threadIdx.x;
    float4 v4 = *((const float4*)(in + row * 1024) + tid);
    float v[4] = {v4.x, v4.y, v4.z, v4.w};
    float s1 = v[0] + v[1] + v[2] + v[3];
    float s2 = v[0] * v[0] + v[1] * v[1] + v[2] * v[2] + v[3] * v[3];
#pragma unroll
    for (int m = 32; m >= 1; m >>= 1) {
        s1 += __shfl_xor(s1, m);
        s2 += __shfl_xor(s2, m);
    }
    __shared__ float r1[4], r2[4];
    int w = tid >> 6;
    if ((tid & 63) == 0) { r1[w] = s1; r2[w] = s2; }
    __syncthreads();
    s1 = r1[0] + r1[1] + r1[2] + r1[3];
    s2 = r2[0] + r2[1] + r2[2] + r2[3];
    float mu = s1 * (1.0f / 1024.0f);
    float var = s2 * (1.0f / 1024.0f) - mu * mu;
    float inv = rsqrtf(var + 1e-5f);
    float y[4];
#pragma unroll
    for (int i = 0; i < 4; i++)
        y[i] = (v[i] - mu) * inv * g[tid * 4 + i] + b[tid * 4 + i];
    unsigned int lo = (unsigned int)f2bf(y[0]) | ((unsigned int)f2bf(y[1]) << 16);
    unsigned int hi = (unsigned int)f2bf(y[2]) | ((unsigned int)f2bf(y[3]) << 16);
    *(uint2*)(out + row * 1024 + tid * 4) = make_uint2(lo, hi);
}

// ---------------- generic 64x64 MFMA GEMM tile, bf16 A and B^T, fp32 acc ----------------
// Normal:  off = (m>>11)*cBatch + (m&2047)*ldc + n
// TRANSC:  off = (m>>11)*cBatch + n*ldc + (m&2047)     (C transposed per batch)
template <typename OutT, int RELU, int TRANSC>
__device__ __forceinline__ void gemm_core(
    const ushort_t* __restrict__ A, int lda,
    const ushort_t* __restrict__ Bt, int ldb, int K,
    OutT* __restrict__ C, long cBatch, int ldc,
    const float* __restrict__ bias,
    const float* __restrict__ resid,
    int m0, int n0, ushort_t* As, ushort_t* Bs) {
    int tid = threadIdx.x;
    int lane = tid & 63, w = tid >> 6;
    int ln = lane & 15, quad = lane >> 4;
    int srow = tid >> 2, scol = (tid & 3) * 8;

    floatx4 acc[4] = {{0, 0, 0, 0}, {0, 0, 0, 0}, {0, 0, 0, 0}, {0, 0, 0, 0}};

    const ushort_t* gA = A + (long)(m0 + srow) * lda + scol;
    const ushort_t* gB = Bt + (long)(n0 + srow) * ldb + scol;
    ushort_t* sA = As + srow * 40 + scol;
    ushort_t* sB = Bs + srow * 40 + scol;

    for (int k0 = 0; k0 < K; k0 += 32) {
        __syncthreads();
        *(int4*)sA = *(const int4*)(gA + k0);
        *(int4*)sB = *(const int4*)(gB + k0);
        __syncthreads();
        short8 af = *(const short8*)(As + (w * 16 + ln) * 40 + quad * 8);
#pragma unroll
        for (int j = 0; j < 4; j++) {
            short8 bf = *(const short8*)(Bs + (j * 16 + ln) * 40 + quad * 8);
            acc[j] = __builtin_amdgcn_mfma_f32_16x16x32_bf16(af, bf, acc[j], 0, 0, 0);
        }
    }
#pragma unroll
    for (int j = 0; j < 4; j++) {
        int gn = n0 + j * 16 + ln;
        float bv = bias ? bias[gn] : 0.0f;
#pragma unroll
        for (int r = 0; r < 4; r++) {
            int gm = m0 + w * 16 + quad * 4 + r;
            long off;
            if (TRANSC)
                off = (long)(gm >> 11) * cBatch + (long)gn * ldc + (gm & 2047);
            else
                off = (long)(gm >> 11) * cBatch + (long)(gm & 2047) * ldc + gn;
            float val = acc[j][r] + bv;
            if (RELU) val = fmaxf(val, 0.0f);
            if (resid) val += resid[off];
            if constexpr (sizeof(OutT) == 2)
                C[off] = (OutT)f2bf(val);
            else
                C[off] = (OutT)val;
        }
    }
}

__global__ __launch_bounds__(256) void gemm_f32out_kernel(
    const ushort_t* __restrict__ A, int lda,
    const ushort_t* __restrict__ Bt, int ldb, int K,
    float* __restrict__ C, long cBatch, int ldc,
    const float* __restrict__ bias, const float* __restrict__ resid) {
    __shared__ ushort_t As[64 * 40];
    __shared__ ushort_t Bs[64 * 40];
    gemm_core<float, 0, 0>(A, lda, Bt, ldb, K, C, cBatch, ldc, bias, resid,
                           blockIdx.x * 64, blockIdx.y * 64, As, Bs);
}

__global__ __launch_bounds__(256) void gemm_bf16out_relu_kernel(
    const ushort_t* __restrict__ A, int lda,
    const ushort_t* __restrict__ Bt, int ldb, int K,
    ushort_t* __restrict__ C, long cBatch, int ldc,
    const float* __restrict__ bias) {
    __shared__ ushort_t As[64 * 40];
    __shared__ ushort_t Bs[64 * 40];
    gemm_core<ushort_t, 1, 0>(A, lda, Bt, ldb, K, C, cBatch, ldc, bias, nullptr,
                              blockIdx.x * 64, blockIdx.y * 64, As, Bs);
}

// Q/K: z = mat*16 + h; writes q/k in [B,H,T,DH] bf16
__global__ __launch_bounds__(256) void gemm_qk_kernel(
    const ushort_t* __restrict__ xn,
    const ushort_t* __restrict__ WqT, const ushort_t* __restrict__ WkT,
    const float* __restrict__ bq, const float* __restrict__ bk,
    ushort_t* __restrict__ qb, ushort_t* __restrict__ kb) {
    __shared__ ushort_t As[64 * 40];
    __shared__ ushort_t Bs[64 * 40];
    int z = blockIdx.z;
    int mat = z >> 4, h = z & 15;
    const ushort_t* Bt = (mat == 0 ? WqT : WkT) + (long)h * 64 * 1024;
    const float* bias = (mat == 0 ? bq : bk) + h * 64;
    ushort_t* C = (mat == 0 ? qb : kb) + (long)h * 2048 * 64;
    gemm_core<ushort_t, 0, 0>(xn, 1024, Bt, 1024, 1024, C, (long)16 * 2048 * 64, 64,
                              bias, nullptr, blockIdx.x * 64, 0, As, Bs);
}

// V: writes vt in [B,H,DH,T] bf16 (transposed-C epilogue)
__global__ __launch_bounds__(256) void gemm_vt_kernel(
    const ushort_t* __restrict__ xn, const ushort_t* __restrict__ WvT,
    const float* __restrict__ bv, ushort_t* __restrict__ vtb) {
    __shared__ ushort_t As[64 * 40];
    __shared__ ushort_t Bs[64 * 40];
    int h = blockIdx.z;
    gemm_core<ushort_t, 0, 1>(xn, 1024, WvT + (long)h * 64 * 1024, 1024, 1024,
                              vtb + (long)h * 64 * 2048, (long)16 * 64 * 2048, 2048,
                              bv + h * 64, nullptr, blockIdx.x * 64, 0, As, Bs);
}

// ---------------- MFMA flash attention ----------------
// grid (T/64, H, B); 4 waves; wave w owns q rows t0+w*16..+15. Online softmax.
// q,k: [B,H,T,64]; vt: [B,H,64,T]; o: [B,T,H*64] bf16
#define LDK 72
__global__ __launch_bounds__(256) void attn_kernel(
    const ushort_t* __restrict__ q, const ushort_t* __restrict__ k,
    const ushort_t* __restrict__ vt, ushort_t* __restrict__ o) {
    __shared__ ushort_t Klds[64 * LDK];
    __shared__ ushort_t Vlds[64 * LDK];
    __shared__ ushort_t Plds[4 * 16 * LDK];
    int b = blockIdx.z, h = blockIdx.y;
    int t0 = blockIdx.x * 64;
    int tid = threadIdx.x;
    int w = tid >> 6, lane = tid & 63;
    int ln = lane & 15, quad = lane >> 4;
    long bh = (long)b * 16 + h;

    // Q fragments, x8 (= sqrt(DH)) folded in (exact in bf16)
    const ushort_t* qrow = q + (bh * 2048 + t0 + w * 16 + ln) * 64;
    short8 qf[2];
#pragma unroll
    for (int s = 0; s < 2; s++) {
        ushortx8 t = *(const ushortx8*)(qrow + s * 32 + quad * 8);
#pragma unroll
        for (int j = 0; j < 8; j++) qf[s][j] = (short)f2bf(b2f(t[j]) * 8.0f);
    }

    floatx4 O[4] = {{0, 0, 0, 0}, {0, 0, 0, 0}, {0, 0, 0, 0}, {0, 0, 0, 0}};
    float m_i[4] = {-1e30f, -1e30f, -1e30f, -1e30f};
    float l_i[4] = {0, 0, 0, 0};

    int srow = tid >> 2, scol = (tid & 3) * 16;
    const ushort_t* gK = k + (bh * 2048 + srow) * 64 + scol;
    const ushort_t* gV = vt + (bh * 64 + srow) * 2048 + scol;
    ushort_t* sK = Klds + srow * LDK + scol;
    ushort_t* sV = Vlds + srow * LDK + scol;
    ushort_t* Pw = Plds + w * 16 * LDK;

    for (int kv0 = 0; kv0 < 2048; kv0 += 64) {
        __syncthreads();
        *(uint4*)sK = *(const uint4*)(gK + (long)kv0 * 64);
        *(uint4*)(sK + 8) = *(const uint4*)(gK + (long)kv0 * 64 + 8);
        *(uint4*)sV = *(const uint4*)(gV + kv0);
        *(uint4*)(sV + 8) = *(const uint4*)(gV + kv0 + 8);
        __syncthreads();

        // S = Q.K^T  (C layout: row=quad*4+r (q), col=ln (kv))
        floatx4 S[4] = {{0, 0, 0, 0}, {0, 0, 0, 0}, {0, 0, 0, 0}, {0, 0, 0, 0}};
#pragma unroll
        for (int s = 0; s < 2; s++) {
#pragma unroll
            for (int nc = 0; nc < 4; nc++) {
                short8 kfrag = *(const short8*)(Klds + (nc * 16 + ln) * LDK + s * 32 + quad * 8);
                S[nc] = __builtin_amdgcn_mfma_f32_16x16x32_bf16(qf[s], kfrag, S[nc], 0, 0, 0);
            }
        }
        // online softmax row stats
        float newm[4], alpha[4], rs[4];
#pragma unroll
        for (int r = 0; r < 4; r++) {
            float mx = fmaxf(fmaxf(S[0][r], S[1][r]), fmaxf(S[2][r], S[3][r]));
#pragma unroll
            for (int msk = 1; msk <= 8; msk <<= 1) mx = fmaxf(mx, __shfl_xor(mx, msk));
            newm[r] = fmaxf(m_i[r], mx);
            alpha[r] = __expf(m_i[r] - newm[r]);
            m_i[r] = newm[r];
            rs[r] = 0.0f;
        }
        // P = exp(S - m), store to wave-private LDS (A-operand staging)
#pragma unroll
        for (int nc = 0; nc < 4; nc++) {
#pragma unroll
            for (int r = 0; r < 4; r++) {
                float p = __expf(S[nc][r] - newm[r]);
                rs[r] += p;
                Pw[(quad * 4 + r) * LDK + nc * 16 + ln] = f2bf(p);
            }
        }
#pragma unroll
        for (int r = 0; r < 4; r++) {
#pragma unroll
            for (int msk = 1; msk <= 8; msk <<= 1) rs[r] += __shfl_xor(rs[r], msk);
            l_i[r] = l_i[r] * alpha[r] + rs[r];
        }
        // rescale O, then O += P.V
#pragma unroll
        for (int dc = 0; dc < 4; dc++)
#pragma unroll
            for (int r = 0; r < 4; r++) O[dc][r] *= alpha[r];
#pragma unroll
        for (int s = 0; s < 2; s++) {
            short8 pf = *(const short8*)(Pw + ln * LDK + s * 32 + quad * 8);
#pragma unroll
            for (int dc = 0; dc < 4; dc++) {
                short8 vfrag = *(const short8*)(Vlds + (dc * 16 + ln) * LDK + s * 32 + quad * 8);
                O[dc] = __builtin_amdgcn_mfma_f32_16x16x32_bf16(pf, vfrag, O[dc], 0, 0, 0);
            }
        }
    }
    // epilogue: o[b][t][h*64+d] = O/l
#pragma unroll
    for (int r = 0; r < 4; r++) {
        float inv = 1.0f / l_i[r];
        int t = t0 + w * 16 + quad * 4 + r;
        ushort_t* orow = o + ((long)b * 2048 + t) * 1024 + h * 64;
#pragma unroll
        for (int dc = 0; dc < 4; dc++) orow[dc * 16 + ln] = f2bf(O[dc][r] * inv);
    }
}

extern "C" void kernel_launch(void* const* d_in, const int* in_sizes, int n_in,
                              void* d_out, int out_size, void* d_ws, size_t ws_size,
                              hipStream_t stream) {
    const float* x   = (const float*)d_in[0];
    const float* Wq  = (const float*)d_in[1];
    const float* bq  = (const float*)d_in[2];
    const float* Wk  = (const float*)d_in[3];
    const float* bk  = (const float*)d_in[4];
    const float* Wv  = (const float*)d_in[5];
    const float* bv  = (const float*)d_in[6];
    const float* Wo  = (const float*)d_in[7];
    const float* bo  = (const float*)d_in[8];
    const float* g1  = (const float*)d_in[9];
    const float* be1 = (const float*)d_in[10];
    const float* g2  = (const float*)d_in[11];
    const float* be2 = (const float*)d_in[12];
    const float* W1  = (const float*)d_in[13];
    const float* b1  = (const float*)d_in[14];
    const float* W2  = (const float*)d_in[15];
    const float* b2  = (const float*)d_in[16];
    float* out = (float*)d_out;

    const long MB = 1 << 20;
    char* w = (char*)d_ws;
    ushort_t* xn  = (ushort_t*)(w);            // [8192,1024] bf16; reused as attn output o
    float*    x2  = (float*)(w + 16 * MB);     // [8192,1024] f32
    ushort_t* qb  = (ushort_t*)(w + 48 * MB);  // [B,H,T,DH] bf16
    ushort_t* kb  = (ushort_t*)(w + 64 * MB);
    ushort_t* vtb = (ushort_t*)(w + 80 * MB);  // [B,H,DH,T] bf16
    ushort_t* xn2 = qb;                        // alias (qb dead after attention)
    ushort_t* h1  = (ushort_t*)(w + 64 * MB);  // [8192,2048] bf16 (kb/vtb dead)
    ushort_t* WqT = (ushort_t*)(w + 96 * MB);  // [H,DH,C]
    ushort_t* WkT = (ushort_t*)(w + 98 * MB);
    ushort_t* WvT = (ushort_t*)(w + 100 * MB);
    ushort_t* WoT = (ushort_t*)(w + 102 * MB); // [C,C]^T
    ushort_t* W1T = (ushort_t*)(w + 104 * MB); // [DFF,C]
    ushort_t* W2T = (ushort_t*)(w + 112 * MB); // [C,DFF]  (ends at 120 MB)

    dim3 tb(32, 8);
    transpose_kernel<<<dim3(32, 2, 16), tb, 0, stream>>>(Wq, WqT, 1024, 64);
    transpose_kernel<<<dim3(32, 2, 16), tb, 0, stream>>>(Wk, WkT, 1024, 64);
    transpose_kernel<<<dim3(32, 2, 16), tb, 0, stream>>>(Wv, WvT, 1024, 64);
    transpose_kernel<<<dim3(32, 32, 1), tb, 0, stream>>>(Wo, WoT, 1024, 1024);
    transpose_kernel<<<dim3(32, 128, 1), tb, 0, stream>>>(W1, W1T, 1024, 4096);
    transpose_kernel<<<dim3(128, 32, 1), tb, 0, stream>>>(W2, W2T, 4096, 1024);

    ln_kernel<<<8192, 256, 0, stream>>>(x, xn, g1, be1);
    gemm_qk_kernel<<<dim3(128, 1, 32), 256, 0, stream>>>(xn, WqT, WkT, bq, bk, qb, kb);
    gemm_vt_kernel<<<dim3(128, 1, 16), 256, 0, stream>>>(xn, WvT, bv, vtb);
    attn_kernel<<<dim3(32, 16, 4), 256, 0, stream>>>(qb, kb, vtb, xn /* o */);
    // x2 = x + o @ Wo + bo   (fp32 out)
    gemm_f32out_kernel<<<dim3(128, 16), 256, 0, stream>>>(xn, 1024, WoT, 1024, 1024,
                                                          x2, 2048L * 1024, 1024, bo, x);
    ln_kernel<<<8192, 256, 0, stream>>>((const float*)x2, xn2, g2, be2);
    // FFN in two DFF=2048 halves to keep ws under 120 MB
    gemm_bf16out_relu_kernel<<<dim3(128, 32), 256, 0, stream>>>(
        xn2, 1024, W1T, 1024, 1024, h1, 2048L * 2048, 2048, b1);
    gemm_f32out_kernel<<<dim3(128, 16), 256, 0, stream>>>(
        h1, 2048, W2T, 4096, 2048, out, 2048L * 1024, 1024, b2, x2);
    gemm_bf16out_relu_kernel<<<dim3(128, 32), 256, 0, stream>>>(
        xn2, 1024, W1T + 2048L * 1024, 1024, 1024, h1, 2048L * 2048, 2048, b1 + 2048);
    gemm_f32out_kernel<<<dim3(128, 16), 256, 0, stream>>>(
        h1, 2048, W2T + 2048, 4096, 2048, out, 2048L * 1024, 1024, nullptr, out);
}

// Round 4
// 790.784 us; speedup vs baseline: 9.8645x; 1.1190x over previous
//
#include <hip/hip_runtime.h>
#include <hip/hip_bf16.h>
#include <stdint.h>

typedef unsigned short ushort_t;
typedef short short8 __attribute__((ext_vector_type(8)));
typedef unsigned short ushortx8 __attribute__((ext_vector_type(8)));
typedef float floatx4 __attribute__((ext_vector_type(4)));

__device__ __forceinline__ float b2f(ushort_t u) {
    return __uint_as_float(((unsigned int)u) << 16);
}
__device__ __forceinline__ ushort_t f2bf(float f) {
    unsigned int u = __float_as_uint(f);
    unsigned int r = u + 0x7FFFu + ((u >> 16) & 1u);
    return (ushort_t)(r >> 16);
}
// async global->LDS, 16B per lane; lds base must be wave-uniform, lanes land at base+lane*16
__device__ __forceinline__ void gll16(const void* g, void* l) {
    __builtin_amdgcn_global_load_lds((const __attribute__((address_space(1))) unsigned int*)g,
                                     (__attribute__((address_space(3))) unsigned int*)l,
                                     16, 0, 0);
}

// ---------------- transpose + downcast: out_bf16[n*K + k] = in_f32[k*N + n], batched ----
__global__ void transpose_kernel(const float* __restrict__ in, ushort_t* __restrict__ out,
                                 int K, int N) {
    __shared__ float tile[32][33];
    in += (long)blockIdx.z * K * N;
    out += (long)blockIdx.z * K * N;
    int k0 = blockIdx.x * 32, n0 = blockIdx.y * 32;
    int x = threadIdx.x, y = threadIdx.y;  // (32, 8)
#pragma unroll
    for (int i = 0; i < 4; i++)
        tile[y + 8 * i][x] = in[(long)(k0 + y + 8 * i) * N + n0 + x];
    __syncthreads();
#pragma unroll
    for (int i = 0; i < 4; i++)
        out[(long)(n0 + y + 8 * i) * K + k0 + x] = f2bf(tile[x][y + 8 * i]);
}

// ---------------- LayerNorm over C=1024, f32 in -> bf16 out ----------------
__global__ __launch_bounds__(256) void ln_kernel(const float* __restrict__ in,
                                                 ushort_t* __restrict__ out,
                                                 const float* __restrict__ g,
                                                 const float* __restrict__ b) {
    long row = blockIdx.x;
    int tid = threadIdx.x;
    float4 v4 = *((const float4*)(in + row * 1024) + tid);
    float v[4] = {v4.x, v4.y, v4.z, v4.w};
    float s1 = v[0] + v[1] + v[2] + v[3];
    float s2 = v[0] * v[0] + v[1] * v[1] + v[2] * v[2] + v[3] * v[3];
#pragma unroll
    for (int m = 32; m >= 1; m >>= 1) {
        s1 += __shfl_xor(s1, m);
        s2 += __shfl_xor(s2, m);
    }
    __shared__ float r1[4], r2[4];
    int w = tid >> 6;
    if ((tid & 63) == 0) { r1[w] = s1; r2[w] = s2; }
    __syncthreads();
    s1 = r1[0] + r1[1] + r1[2] + r1[3];
    s2 = r2[0] + r2[1] + r2[2] + r2[3];
    float mu = s1 * (1.0f / 1024.0f);
    float var = s2 * (1.0f / 1024.0f) - mu * mu;
    float inv = rsqrtf(var + 1e-5f);
    float y[4];
#pragma unroll
    for (int i = 0; i < 4; i++)
        y[i] = (v[i] - mu) * inv * g[tid * 4 + i] + b[tid * 4 + i];
    unsigned int lo = (unsigned int)f2bf(y[0]) | ((unsigned int)f2bf(y[1]) << 16);
    unsigned int hi = (unsigned int)f2bf(y[2]) | ((unsigned int)f2bf(y[3]) << 16);
    *(uint2*)(out + row * 1024 + tid * 4) = make_uint2(lo, hi);
}

// ---------------- m97-style 128x128 MFMA GEMM, bf16 A and B^T, global_load_lds ----------
// Normal:  off = (m>>11)*cBatch + (m&2047)*ldc + n
// TRANSC:  off = (m>>11)*cBatch + n*ldc + (m&2047)
template <typename OutT, int RELU, int TRANSC>
__device__ __forceinline__ void gemm128(
    const ushort_t* __restrict__ A, int lda,
    const ushort_t* __restrict__ Bt, int ldb, int K,
    OutT* __restrict__ C, long cBatch, int ldc,
    const float* __restrict__ bias, const float* __restrict__ resid,
    ushort_t* As, ushort_t* Bs) {
    int m0 = blockIdx.x * 128, n0 = blockIdx.y * 128;
    int tid = threadIdx.x, lane = tid & 63, w = tid >> 6;
    int ln = lane & 15, quad = lane >> 4;
    int wr = w >> 1, wc = w & 1;
    int lr = lane >> 2, lc = (lane & 3) * 8;

    floatx4 acc[4][4];
#pragma unroll
    for (int a = 0; a < 4; a++)
#pragma unroll
        for (int bb = 0; bb < 4; bb++) acc[a][bb] = floatx4{0, 0, 0, 0};

    for (int k0 = 0; k0 < K; k0 += 32) {
        __syncthreads();
#pragma unroll
        for (int i = 0; i < 4; i++) {
            int id = w * 4 + i;      // wave-uniform
            int blk = id & 7;
            int row = blk * 16 + lr;
            if (id < 8)
                gll16(A + (long)(m0 + row) * lda + k0 + lc, As + blk * 512);
            else
                gll16(Bt + (long)(n0 + row) * ldb + k0 + lc, Bs + blk * 512);
        }
        __syncthreads();  // drains vmcnt (global_load_lds) + barrier
        short8 af[4], bf[4];
#pragma unroll
        for (int j = 0; j < 4; j++) {
            af[j] = *(const short8*)(As + (wr * 64 + j * 16 + ln) * 32 + quad * 8);
            bf[j] = *(const short8*)(Bs + (wc * 64 + j * 16 + ln) * 32 + quad * 8);
        }
#pragma unroll
        for (int a = 0; a < 4; a++)
#pragma unroll
            for (int bb = 0; bb < 4; bb++)
                acc[a][bb] = __builtin_amdgcn_mfma_f32_16x16x32_bf16(af[a], bf[bb], acc[a][bb], 0, 0, 0);
    }
#pragma unroll
    for (int bb = 0; bb < 4; bb++) {
        int gn = n0 + wc * 64 + bb * 16 + ln;
        float bv = bias ? bias[gn] : 0.0f;
#pragma unroll
        for (int a = 0; a < 4; a++) {
#pragma unroll
            for (int r = 0; r < 4; r++) {
                int gm = m0 + wr * 64 + a * 16 + quad * 4 + r;
                long off;
                if (TRANSC)
                    off = (long)(gm >> 11) * cBatch + (long)gn * ldc + (gm & 2047);
                else
                    off = (long)(gm >> 11) * cBatch + (long)(gm & 2047) * ldc + gn;
                float val = acc[a][bb][r] + bv;
                if (RELU) val = fmaxf(val, 0.0f);
                if (resid) val += resid[off];
                if constexpr (sizeof(OutT) == 2)
                    C[off] = (OutT)f2bf(val);
                else
                    C[off] = (OutT)val;
            }
        }
    }
}

__global__ __launch_bounds__(256) void gemm128_bf16_kernel(
    const ushort_t* __restrict__ A, int lda, const ushort_t* __restrict__ Bt, int ldb, int K,
    ushort_t* __restrict__ C, long cBatch, int ldc, const float* __restrict__ bias) {
    __shared__ ushort_t As[128 * 32];
    __shared__ ushort_t Bs[128 * 32];
    gemm128<ushort_t, 0, 0>(A, lda, Bt, ldb, K, C, cBatch, ldc, bias, nullptr, As, Bs);
}

__global__ __launch_bounds__(256) void gemm128_bf16_relu_kernel(
    const ushort_t* __restrict__ A, int lda, const ushort_t* __restrict__ Bt, int ldb, int K,
    ushort_t* __restrict__ C, long cBatch, int ldc, const float* __restrict__ bias) {
    __shared__ ushort_t As[128 * 32];
    __shared__ ushort_t Bs[128 * 32];
    gemm128<ushort_t, 1, 0>(A, lda, Bt, ldb, K, C, cBatch, ldc, bias, nullptr, As, Bs);
}

__global__ __launch_bounds__(256) void gemm128_bf16_tc_kernel(
    const ushort_t* __restrict__ A, int lda, const ushort_t* __restrict__ Bt, int ldb, int K,
    ushort_t* __restrict__ C, long cBatch, int ldc, const float* __restrict__ bias) {
    __shared__ ushort_t As[128 * 32];
    __shared__ ushort_t Bs[128 * 32];
    gemm128<ushort_t, 0, 1>(A, lda, Bt, ldb, K, C, cBatch, ldc, bias, nullptr, As, Bs);
}

__global__ __launch_bounds__(256) void gemm128_f32_kernel(
    const ushort_t* __restrict__ A, int lda, const ushort_t* __restrict__ Bt, int ldb, int K,
    float* __restrict__ C, long cBatch, int ldc,
    const float* __restrict__ bias, const float* __restrict__ resid) {
    __shared__ ushort_t As[128 * 32];
    __shared__ ushort_t Bs[128 * 32];
    gemm128<float, 0, 0>(A, lda, Bt, ldb, K, C, cBatch, ldc, bias, resid, As, Bs);
}

// ---------------- MFMA flash attention v2 ----------------
// q,k: [B,T,1024] bf16 (head h at cols h*64..); vt: [B,H,64,2048] bf16; o: [B,T,1024] bf16
// 1024 blocks (XCD-swizzled), 4 waves, wave owns 32 q rows (2 subtiles of 16).
__global__ __launch_bounds__(256, 3) void attn_kernel(
    const ushort_t* __restrict__ q, const ushort_t* __restrict__ k,
    const ushort_t* __restrict__ vt, ushort_t* __restrict__ o) {
    __shared__ ushort_t Klds[2 * 64 * 32];   // [s-half][kv row][32]
    __shared__ ushort_t Vlds[2 * 64 * 32];   // [s-half][d row][32]
    __shared__ ushort_t Plds[4 * 32 * 68];   // per-wave 32 rows, stride 68 (bank-friendly)
    int flat = blockIdx.x;
    // XCD swizzle: all 16 q-tiles of one (b,h) share flat%8 -> same XCD -> K/V L2 reuse
    int bh = (flat & 7) * 8 + (flat >> 7);
    int xt = (flat >> 3) & 15;
    int b = bh >> 4, h = bh & 15;
    int t0 = xt * 128;
    int tid = threadIdx.x, lane = tid & 63, w = tid >> 6;
    int ln = lane & 15, quad = lane >> 4;
    int lr = lane >> 2, lc = (lane & 3) * 8;

    // Q fragments, x8 (= sqrt(DH)) folded in (exact in bf16)
    const ushort_t* qbase = q + ((long)b * 2048 + t0 + w * 32) * 1024 + h * 64;
    short8 qf[2][2];
#pragma unroll
    for (int sub = 0; sub < 2; sub++)
#pragma unroll
        for (int s = 0; s < 2; s++) {
            ushortx8 t = *(const ushortx8*)(qbase + (long)(sub * 16 + ln) * 1024 + s * 32 + quad * 8);
#pragma unroll
            for (int j = 0; j < 8; j++) qf[sub][s][j] = (short)f2bf(b2f(t[j]) * 8.0f);
        }

    floatx4 O[2][4];
    float m_i[2][4], l_i[2][4];
#pragma unroll
    for (int sub = 0; sub < 2; sub++)
#pragma unroll
        for (int i = 0; i < 4; i++) {
            O[sub][i] = floatx4{0, 0, 0, 0};
            m_i[sub][i] = -1e30f;
            l_i[sub][i] = 0.0f;
        }

    short8 ones;
#pragma unroll
    for (int j = 0; j < 8; j++) ones[j] = (short)0x3F80;  // bf16 1.0

    ushort_t* Pw = Plds + w * 32 * 68;
    long krow0 = (long)b * 2048 * 1024 + h * 64;
    const ushort_t* vbase = vt + (long)bh * 64 * 2048;

    for (int kv0 = 0; kv0 < 2048; kv0 += 64) {
        __syncthreads();
#pragma unroll
        for (int i = 0; i < 4; i++) {
            int id = w * 4 + i;  // waves 0,1 stage K halves; waves 2,3 stage V halves
            int hh = (id >> 2) & 1, qt = id & 3;
            int row = qt * 16 + lr;
            if (id < 8)
                gll16(k + krow0 + (long)(kv0 + row) * 1024 + hh * 32 + lc,
                      Klds + hh * 2048 + qt * 512);
            else
                gll16(vbase + (long)row * 2048 + kv0 + hh * 32 + lc,
                      Vlds + hh * 2048 + qt * 512);
        }
        __syncthreads();

        // S = Q.K^T : C[q=quad*4+r][kv=nc*16+ln]
        floatx4 S[2][4];
#pragma unroll
        for (int sub = 0; sub < 2; sub++)
#pragma unroll
            for (int nc = 0; nc < 4; nc++) S[sub][nc] = floatx4{0, 0, 0, 0};
#pragma unroll
        for (int s = 0; s < 2; s++)
#pragma unroll
            for (int nc = 0; nc < 4; nc++) {
                short8 kf = *(const short8*)(Klds + s * 2048 + (nc * 16 + ln) * 32 + quad * 8);
                S[0][nc] = __builtin_amdgcn_mfma_f32_16x16x32_bf16(qf[0][s], kf, S[0][nc], 0, 0, 0);
                S[1][nc] = __builtin_amdgcn_mfma_f32_16x16x32_bf16(qf[1][s], kf, S[1][nc], 0, 0, 0);
            }
        // online softmax: row max (in-reg over nc, 4 shuffle hops over ln), P -> LDS
        float alpha[2][4];
#pragma unroll
        for (int sub = 0; sub < 2; sub++) {
#pragma unroll
            for (int r = 0; r < 4; r++) {
                float mx = fmaxf(fmaxf(S[sub][0][r], S[sub][1][r]),
                                 fmaxf(S[sub][2][r], S[sub][3][r]));
#pragma unroll
                for (int msk = 1; msk <= 8; msk <<= 1) mx = fmaxf(mx, __shfl_xor(mx, msk));
                float nm = fmaxf(m_i[sub][r], mx);
                alpha[sub][r] = __expf(m_i[sub][r] - nm);
                m_i[sub][r] = nm;
            }
#pragma unroll
            for (int nc = 0; nc < 4; nc++)
#pragma unroll
                for (int r = 0; r < 4; r++) {
                    float p = __expf(S[sub][nc][r] - m_i[sub][r]);
                    Pw[(sub * 16 + quad * 4 + r) * 68 + nc * 16 + ln] = f2bf(p);
                }
        }
        // P back as A-operand; l via MFMA with ones; O rescale; O += P.V
        short8 pf[2][2];
#pragma unroll
        for (int sub = 0; sub < 2; sub++)
#pragma unroll
            for (int s = 0; s < 2; s++)
                pf[sub][s] = *(const short8*)(Pw + (sub * 16 + ln) * 68 + s * 32 + quad * 8);
#pragma unroll
        for (int sub = 0; sub < 2; sub++) {
            floatx4 L = floatx4{0, 0, 0, 0};
            L = __builtin_amdgcn_mfma_f32_16x16x32_bf16(pf[sub][0], ones, L, 0, 0, 0);
            L = __builtin_amdgcn_mfma_f32_16x16x32_bf16(pf[sub][1], ones, L, 0, 0, 0);
#pragma unroll
            for (int r = 0; r < 4; r++) l_i[sub][r] = l_i[sub][r] * alpha[sub][r] + L[r];
#pragma unroll
            for (int dc = 0; dc < 4; dc++)
#pragma unroll
                for (int r = 0; r < 4; r++) O[sub][dc][r] *= alpha[sub][r];
        }
#pragma unroll
        for (int s = 0; s < 2; s++)
#pragma unroll
            for (int dc = 0; dc < 4; dc++) {
                short8 vf = *(const short8*)(Vlds + s * 2048 + (dc * 16 + ln) * 32 + quad * 8);
                O[0][dc] = __builtin_amdgcn_mfma_f32_16x16x32_bf16(pf[0][s], vf, O[0][dc], 0, 0, 0);
                O[1][dc] = __builtin_amdgcn_mfma_f32_16x16x32_bf16(pf[1][s], vf, O[1][dc], 0, 0, 0);
            }
    }
    // epilogue: o[b][t][h*64+d] = O/l
#pragma unroll
    for (int sub = 0; sub < 2; sub++)
#pragma unroll
        for (int r = 0; r < 4; r++) {
            float inv = 1.0f / l_i[sub][r];
            int t = t0 + w * 32 + sub * 16 + quad * 4 + r;
            ushort_t* orow = o + ((long)b * 2048 + t) * 1024 + h * 64;
#pragma unroll
            for (int dc = 0; dc < 4; dc++) orow[dc * 16 + ln] = f2bf(O[sub][dc][r] * inv);
        }
}

extern "C" void kernel_launch(void* const* d_in, const int* in_sizes, int n_in,
                              void* d_out, int out_size, void* d_ws, size_t ws_size,
                              hipStream_t stream) {
    const float* x   = (const float*)d_in[0];
    const float* Wq  = (const float*)d_in[1];
    const float* bq  = (const float*)d_in[2];
    const float* Wk  = (const float*)d_in[3];
    const float* bk  = (const float*)d_in[4];
    const float* Wv  = (const float*)d_in[5];
    const float* bv  = (const float*)d_in[6];
    const float* Wo  = (const float*)d_in[7];
    const float* bo  = (const float*)d_in[8];
    const float* g1  = (const float*)d_in[9];
    const float* be1 = (const float*)d_in[10];
    const float* g2  = (const float*)d_in[11];
    const float* be2 = (const float*)d_in[12];
    const float* W1  = (const float*)d_in[13];
    const float* b1  = (const float*)d_in[14];
    const float* W2  = (const float*)d_in[15];
    const float* b2  = (const float*)d_in[16];
    float* out = (float*)d_out;

    const long MB = 1 << 20;
    char* w = (char*)d_ws;
    ushort_t* xn  = (ushort_t*)(w);            // [8192,1024] bf16; reused as attn output o
    float*    x2  = (float*)(w + 16 * MB);     // [8192,1024] f32
    ushort_t* qb  = (ushort_t*)(w + 48 * MB);  // [B,T,C] bf16
    ushort_t* kb  = (ushort_t*)(w + 64 * MB);  // [B,T,C] bf16
    ushort_t* vtb = (ushort_t*)(w + 80 * MB);  // [B,H,DH,T] bf16
    ushort_t* xn2 = qb;                        // alias (qb dead after attention)
    ushort_t* h1  = (ushort_t*)(w + 64 * MB);  // [8192,2048] bf16 (kb/vtb dead)
    ushort_t* WqT = (ushort_t*)(w + 96 * MB);  // [H,DH,C] = [1024,1024] row n = h*64+d
    ushort_t* WkT = (ushort_t*)(w + 98 * MB);
    ushort_t* WvT = (ushort_t*)(w + 100 * MB);
    ushort_t* WoT = (ushort_t*)(w + 102 * MB); // [C,C]^T
    ushort_t* W1T = (ushort_t*)(w + 104 * MB); // [DFF,C]
    ushort_t* W2T = (ushort_t*)(w + 112 * MB); // [C,DFF]  (ends at 120 MB)

    dim3 tb(32, 8);
    transpose_kernel<<<dim3(32, 2, 16), tb, 0, stream>>>(Wq, WqT, 1024, 64);
    transpose_kernel<<<dim3(32, 2, 16), tb, 0, stream>>>(Wk, WkT, 1024, 64);
    transpose_kernel<<<dim3(32, 2, 16), tb, 0, stream>>>(Wv, WvT, 1024, 64);
    transpose_kernel<<<dim3(32, 32, 1), tb, 0, stream>>>(Wo, WoT, 1024, 1024);
    transpose_kernel<<<dim3(32, 128, 1), tb, 0, stream>>>(W1, W1T, 1024, 4096);
    transpose_kernel<<<dim3(128, 32, 1), tb, 0, stream>>>(W2, W2T, 4096, 1024);

    ln_kernel<<<8192, 256, 0, stream>>>(x, xn, g1, be1);
    // q, k: [B,T,C]; v: transposed-C -> [B,H,DH,T]
    gemm128_bf16_kernel<<<dim3(64, 8), 256, 0, stream>>>(xn, 1024, WqT, 1024, 1024,
                                                         qb, 2048L * 1024, 1024, bq);
    gemm128_bf16_kernel<<<dim3(64, 8), 256, 0, stream>>>(xn, 1024, WkT, 1024, 1024,
                                                         kb, 2048L * 1024, 1024, bk);
    gemm128_bf16_tc_kernel<<<dim3(64, 8), 256, 0, stream>>>(xn, 1024, WvT, 1024, 1024,
                                                            vtb, 16L * 64 * 2048, 2048, bv);
    attn_kernel<<<1024, 256, 0, stream>>>(qb, kb, vtb, xn /* o */);
    // x2 = x + o @ Wo + bo   (fp32 out)
    gemm128_f32_kernel<<<dim3(64, 8), 256, 0, stream>>>(xn, 1024, WoT, 1024, 1024,
                                                        x2, 2048L * 1024, 1024, bo, x);
    ln_kernel<<<8192, 256, 0, stream>>>((const float*)x2, xn2, g2, be2);
    // FFN in two DFF=2048 halves (ws budget)
    gemm128_bf16_relu_kernel<<<dim3(64, 16), 256, 0, stream>>>(
        xn2, 1024, W1T, 1024, 1024, h1, 2048L * 2048, 2048, b1);
    gemm128_f32_kernel<<<dim3(64, 8), 256, 0, stream>>>(
        h1, 2048, W2T, 4096, 2048, out, 2048L * 1024, 1024, b2, x2);
    gemm128_bf16_relu_kernel<<<dim3(64, 16), 256, 0, stream>>>(
        xn2, 1024, W1T + 2048L * 1024, 1024, 1024, h1, 2048L * 2048, 2048, b1 + 2048);
    gemm128_f32_kernel<<<dim3(64, 8), 256, 0, stream>>>(
        h1, 2048, W2T + 2048, 4096, 2048, out, 2048L * 1024, 1024, nullptr, out);
}

// Round 5
// 702.592 us; speedup vs baseline: 11.1028x; 1.1255x over previous
//
#include <hip/hip_runtime.h>
#include <hip/hip_bf16.h>
#include <stdint.h>

typedef unsigned short ushort_t;
typedef short short8 __attribute__((ext_vector_type(8)));
typedef unsigned short ushortx8 __attribute__((ext_vector_type(8)));
typedef float floatx4 __attribute__((ext_vector_type(4)));

__device__ __forceinline__ float b2f(ushort_t u) {
    return __uint_as_float(((unsigned int)u) << 16);
}
__device__ __forceinline__ ushort_t f2bf(float f) {
    unsigned int u = __float_as_uint(f);
    unsigned int r = u + 0x7FFFu + ((u >> 16) & 1u);
    return (ushort_t)(r >> 16);
}
// async global->LDS, 16B per lane; lds base wave-uniform, lanes land at base+lane*16
__device__ __forceinline__ void gll16(const void* g, void* l) {
    __builtin_amdgcn_global_load_lds((const __attribute__((address_space(1))) unsigned int*)g,
                                     (__attribute__((address_space(3))) unsigned int*)l,
                                     16, 0, 0);
}

// ---------------- transpose + downcast: out_bf16[n*K + k] = in_f32[k*N + n], batched ----
__global__ void transpose_kernel(const float* __restrict__ in, ushort_t* __restrict__ out,
                                 int K, int N) {
    __shared__ float tile[32][33];
    in += (long)blockIdx.z * K * N;
    out += (long)blockIdx.z * K * N;
    int k0 = blockIdx.x * 32, n0 = blockIdx.y * 32;
    int x = threadIdx.x, y = threadIdx.y;  // (32, 8)
#pragma unroll
    for (int i = 0; i < 4; i++)
        tile[y + 8 * i][x] = in[(long)(k0 + y + 8 * i) * N + n0 + x];
    __syncthreads();
#pragma unroll
    for (int i = 0; i < 4; i++)
        out[(long)(n0 + y + 8 * i) * K + k0 + x] = f2bf(tile[x][y + 8 * i]);
}

// concat bias for fused QKV: dst[0..1023]=bq, [1024..2047]=bk, [2048..3071]=bv
__global__ void concat_bias_kernel(const float* __restrict__ bq, const float* __restrict__ bk,
                                   const float* __restrict__ bv, float* __restrict__ dst) {
    int i = blockIdx.x * 256 + threadIdx.x;
    dst[i] = i < 1024 ? bq[i] : (i < 2048 ? bk[i - 1024] : bv[i - 2048]);
}

// ---------------- LayerNorm over C=1024, f32 in -> bf16 out ----------------
__global__ __launch_bounds__(256) void ln_kernel(const float* __restrict__ in,
                                                 ushort_t* __restrict__ out,
                                                 const float* __restrict__ g,
                                                 const float* __restrict__ b) {
    long row = blockIdx.x;
    int tid = threadIdx.x;
    float4 v4 = *((const float4*)(in + row * 1024) + tid);
    float v[4] = {v4.x, v4.y, v4.z, v4.w};
    float s1 = v[0] + v[1] + v[2] + v[3];
    float s2 = v[0] * v[0] + v[1] * v[1] + v[2] * v[2] + v[3] * v[3];
#pragma unroll
    for (int m = 32; m >= 1; m >>= 1) {
        s1 += __shfl_xor(s1, m);
        s2 += __shfl_xor(s2, m);
    }
    __shared__ float r1[4], r2[4];
    int w = tid >> 6;
    if ((tid & 63) == 0) { r1[w] = s1; r2[w] = s2; }
    __syncthreads();
    s1 = r1[0] + r1[1] + r1[2] + r1[3];
    s2 = r2[0] + r2[1] + r2[2] + r2[3];
    float mu = s1 * (1.0f / 1024.0f);
    float var = s2 * (1.0f / 1024.0f) - mu * mu;
    float inv = rsqrtf(var + 1e-5f);
    float y[4];
#pragma unroll
    for (int i = 0; i < 4; i++)
        y[i] = (v[i] - mu) * inv * g[tid * 4 + i] + b[tid * 4 + i];
    unsigned int lo = (unsigned int)f2bf(y[0]) | ((unsigned int)f2bf(y[1]) << 16);
    unsigned int hi = (unsigned int)f2bf(y[2]) | ((unsigned int)f2bf(y[3]) << 16);
    *(uint2*)(out + row * 1024 + tid * 4) = make_uint2(lo, hi);
}

// ------- 128x128 MFMA GEMM, bf16 A and B^T, double-buffered global_load_lds pipeline ----
// MODE 0: off = (m>>11)*cBatch + (m&2047)*ldc + n   (+bias/relu/resid)
// MODE 2 (QKV): n<1024 -> q [B,T,C]; n<2048 -> k (contig after q); n>=2048 -> v^T [B,H,DH,T]
template <typename OutT, int RELU, int MODE>
__device__ __forceinline__ void gemm128(
    const ushort_t* __restrict__ A, int lda,
    const ushort_t* __restrict__ Bt, int ldb, int K,
    OutT* __restrict__ C, long cBatch, int ldc,
    const float* __restrict__ bias, const float* __restrict__ resid,
    ushort_t* As, ushort_t* Bs) {   // each [2][128*32]
    int m0 = blockIdx.x * 128, n0 = blockIdx.y * 128;
    int tid = threadIdx.x, lane = tid & 63, w = tid >> 6;
    int ln = lane & 15, quad = lane >> 4;
    int wr = w >> 1, wc = w & 1;
    int lr = lane >> 2, lc = (lane & 3) * 8;

    auto stage = [&](int k0, int buf) {
#pragma unroll
        for (int i = 0; i < 4; i++) {
            int id = w * 4 + i;  // wave-uniform
            int blk = id & 7;
            int row = blk * 16 + lr;
            if (id < 8)
                gll16(A + (long)(m0 + row) * lda + k0 + lc, As + buf * 4096 + blk * 512);
            else
                gll16(Bt + (long)(n0 + row) * ldb + k0 + lc, Bs + buf * 4096 + blk * 512);
        }
    };

    floatx4 acc[4][4];
#pragma unroll
    for (int a = 0; a < 4; a++)
#pragma unroll
        for (int bb = 0; bb < 4; bb++) acc[a][bb] = floatx4{0, 0, 0, 0};

    stage(0, 0);
    int cur = 0;
    for (int k0 = 0; k0 < K; k0 += 32, cur ^= 1) {
        __syncthreads();  // own staged loads drained; other buffer free
        if (k0 + 32 < K) stage(k0 + 32, cur ^ 1);
        const ushort_t* Ab = As + cur * 4096;
        const ushort_t* Bb = Bs + cur * 4096;
        short8 af[4], bf[4];
#pragma unroll
        for (int j = 0; j < 4; j++) {
            af[j] = *(const short8*)(Ab + (wr * 64 + j * 16 + ln) * 32 + quad * 8);
            bf[j] = *(const short8*)(Bb + (wc * 64 + j * 16 + ln) * 32 + quad * 8);
        }
#pragma unroll
        for (int a = 0; a < 4; a++)
#pragma unroll
            for (int bb = 0; bb < 4; bb++)
                acc[a][bb] = __builtin_amdgcn_mfma_f32_16x16x32_bf16(af[a], bf[bb], acc[a][bb], 0, 0, 0);
    }
#pragma unroll
    for (int bb = 0; bb < 4; bb++) {
        int gn = n0 + wc * 64 + bb * 16 + ln;
        float bv = bias ? bias[gn] : 0.0f;
#pragma unroll
        for (int a = 0; a < 4; a++) {
#pragma unroll
            for (int r = 0; r < 4; r++) {
                int gm = m0 + wr * 64 + a * 16 + quad * 4 + r;
                float val = acc[a][bb][r] + bv;
                if (RELU) val = fmaxf(val, 0.0f);
                if constexpr (MODE == 2) {
                    int gnl = gn & 1023;
                    long off;
                    if (gn < 2048)  // q or k: [2][B,T,1024] contiguous
                        off = (long)(gn >> 10) * 8388608 + (long)(gm >> 11) * 2097152 +
                              (long)(gm & 2047) * 1024 + gnl;
                    else  // v transposed: [B,H,64,2048] at +16M elems
                        off = 16777216L +
                              ((((long)(gm >> 11)) * 16 + (gnl >> 6)) * 64 + (gnl & 63)) * 2048 +
                              (gm & 2047);
                    C[off] = (OutT)f2bf(val);
                } else {
                    long off = (long)(gm >> 11) * cBatch + (long)(gm & 2047) * ldc + gn;
                    if (resid) val += resid[off];
                    if constexpr (sizeof(OutT) == 2)
                        C[off] = (OutT)f2bf(val);
                    else
                        C[off] = (OutT)val;
                }
            }
        }
    }
}

__global__ __launch_bounds__(256) void gemm128_qkv_kernel(
    const ushort_t* __restrict__ A, const ushort_t* __restrict__ Bt,
    ushort_t* __restrict__ C, const float* __restrict__ bias) {
    __shared__ ushort_t As[2 * 128 * 32];
    __shared__ ushort_t Bs[2 * 128 * 32];
    gemm128<ushort_t, 0, 2>(A, 1024, Bt, 1024, 1024, C, 0, 0, bias, nullptr, As, Bs);
}

__global__ __launch_bounds__(256) void gemm128_bf16_relu_kernel(
    const ushort_t* __restrict__ A, int lda, const ushort_t* __restrict__ Bt, int ldb, int K,
    ushort_t* __restrict__ C, long cBatch, int ldc, const float* __restrict__ bias) {
    __shared__ ushort_t As[2 * 128 * 32];
    __shared__ ushort_t Bs[2 * 128 * 32];
    gemm128<ushort_t, 1, 0>(A, lda, Bt, ldb, K, C, cBatch, ldc, bias, nullptr, As, Bs);
}

__global__ __launch_bounds__(256) void gemm128_f32_kernel(
    const ushort_t* __restrict__ A, int lda, const ushort_t* __restrict__ Bt, int ldb, int K,
    float* __restrict__ C, long cBatch, int ldc,
    const float* __restrict__ bias, const float* __restrict__ resid) {
    __shared__ ushort_t As[2 * 128 * 32];
    __shared__ ushort_t Bs[2 * 128 * 32];
    gemm128<float, 0, 0>(A, lda, Bt, ldb, K, C, cBatch, ldc, bias, resid, As, Bs);
}

// ---------------- MFMA flash attention v3: double-buffered K/V, 1 barrier/tile ----------
// q,k: [B,T,1024] bf16 (head h at cols h*64..); vt: [B,H,64,2048] bf16; o: [B,T,1024] bf16
// 1024 blocks (XCD-swizzled), 4 waves, wave owns 32 q rows (2 subtiles of 16).
__global__ __launch_bounds__(256, 3) void attn_kernel(
    const ushort_t* __restrict__ q, const ushort_t* __restrict__ k,
    const ushort_t* __restrict__ vt, ushort_t* __restrict__ o) {
    __shared__ ushort_t Klds[2 * 4096];      // [buf][s-half][kv row 64][32]
    __shared__ ushort_t Vlds[2 * 4096];      // [buf][s-half][d row 64][32]
    __shared__ ushort_t Plds[4 * 32 * 68];   // per-wave 32 rows, stride 68
    int flat = blockIdx.x;
    // XCD swizzle: all 16 q-tiles of one (b,h) share flat%8 -> same XCD L2
    int bh = (flat & 7) * 8 + (flat >> 7);
    int xt = (flat >> 3) & 15;
    int b = bh >> 4, h = bh & 15;
    int t0 = xt * 128;
    int tid = threadIdx.x, lane = tid & 63, w = tid >> 6;
    int ln = lane & 15, quad = lane >> 4;
    int lr = lane >> 2, lc = (lane & 3) * 8;

    // Q fragments, x8 (= sqrt(DH)) folded in (exact in bf16)
    const ushort_t* qbase = q + ((long)b * 2048 + t0 + w * 32) * 1024 + h * 64;
    short8 qf[2][2];
#pragma unroll
    for (int sub = 0; sub < 2; sub++)
#pragma unroll
        for (int s = 0; s < 2; s++) {
            ushortx8 t = *(const ushortx8*)(qbase + (long)(sub * 16 + ln) * 1024 + s * 32 + quad * 8);
#pragma unroll
            for (int j = 0; j < 8; j++) qf[sub][s][j] = (short)f2bf(b2f(t[j]) * 8.0f);
        }

    floatx4 O[2][4];
    float m_i[2][4], l_i[2][4];
#pragma unroll
    for (int sub = 0; sub < 2; sub++)
#pragma unroll
        for (int i = 0; i < 4; i++) {
            O[sub][i] = floatx4{0, 0, 0, 0};
            m_i[sub][i] = -1e30f;
            l_i[sub][i] = 0.0f;
        }

    short8 ones;
#pragma unroll
    for (int j = 0; j < 8; j++) ones[j] = (short)0x3F80;  // bf16 1.0

    ushort_t* Pw = Plds + w * 32 * 68;
    long krow0 = (long)b * 2048 * 1024 + h * 64;
    const ushort_t* vbase = vt + (long)bh * 64 * 2048;

    auto stage = [&](int kv0, int buf) {
#pragma unroll
        for (int i = 0; i < 4; i++) {
            int id = w * 4 + i;  // waves 0,1 -> K halves; waves 2,3 -> V halves
            int hh = (id >> 2) & 1, qt = id & 3;
            int row = qt * 16 + lr;
            if (id < 8)
                gll16(k + krow0 + (long)(kv0 + row) * 1024 + hh * 32 + lc,
                      Klds + buf * 4096 + hh * 2048 + qt * 512);
            else
                gll16(vbase + (long)row * 2048 + kv0 + hh * 32 + lc,
                      Vlds + buf * 4096 + hh * 2048 + qt * 512);
        }
    };

    stage(0, 0);
    int cur = 0;
    for (int t32 = 0; t32 < 32; t32++, cur ^= 1) {
        __syncthreads();  // own staged loads drained -> this buffer ready; other free
        if (t32 < 31) stage((t32 + 1) * 64, cur ^ 1);
        const ushort_t* Kb = Klds + cur * 4096;
        const ushort_t* Vb = Vlds + cur * 4096;

        // S = Q.K^T : C[q=quad*4+r][kv=nc*16+ln]
        floatx4 S[2][4];
#pragma unroll
        for (int sub = 0; sub < 2; sub++)
#pragma unroll
            for (int nc = 0; nc < 4; nc++) S[sub][nc] = floatx4{0, 0, 0, 0};
#pragma unroll
        for (int s = 0; s < 2; s++)
#pragma unroll
            for (int nc = 0; nc < 4; nc++) {
                short8 kf = *(const short8*)(Kb + s * 2048 + (nc * 16 + ln) * 32 + quad * 8);
                S[0][nc] = __builtin_amdgcn_mfma_f32_16x16x32_bf16(qf[0][s], kf, S[0][nc], 0, 0, 0);
                S[1][nc] = __builtin_amdgcn_mfma_f32_16x16x32_bf16(qf[1][s], kf, S[1][nc], 0, 0, 0);
            }
        // online softmax: row max, P -> LDS (bf16)
        float alpha[2][4];
#pragma unroll
        for (int sub = 0; sub < 2; sub++) {
#pragma unroll
            for (int r = 0; r < 4; r++) {
                float mx = fmaxf(fmaxf(S[sub][0][r], S[sub][1][r]),
                                 fmaxf(S[sub][2][r], S[sub][3][r]));
#pragma unroll
                for (int msk = 1; msk <= 8; msk <<= 1) mx = fmaxf(mx, __shfl_xor(mx, msk));
                float nm = fmaxf(m_i[sub][r], mx);
                alpha[sub][r] = __expf(m_i[sub][r] - nm);
                m_i[sub][r] = nm;
            }
#pragma unroll
            for (int nc = 0; nc < 4; nc++)
#pragma unroll
                for (int r = 0; r < 4; r++) {
                    float p = __expf(S[sub][nc][r] - m_i[sub][r]);
                    Pw[(sub * 16 + quad * 4 + r) * 68 + nc * 16 + ln] = f2bf(p);
                }
        }
        // P back as A-operand; l via ones-MFMA; O rescale; O += P.V
        short8 pf[2][2];
#pragma unroll
        for (int sub = 0; sub < 2; sub++)
#pragma unroll
            for (int s = 0; s < 2; s++)
                pf[sub][s] = *(const short8*)(Pw + (sub * 16 + ln) * 68 + s * 32 + quad * 8);
#pragma unroll
        for (int sub = 0; sub < 2; sub++) {
            floatx4 L = floatx4{0, 0, 0, 0};
            L = __builtin_amdgcn_mfma_f32_16x16x32_bf16(pf[sub][0], ones, L, 0, 0, 0);
            L = __builtin_amdgcn_mfma_f32_16x16x32_bf16(pf[sub][1], ones, L, 0, 0, 0);
#pragma unroll
            for (int r = 0; r < 4; r++) l_i[sub][r] = l_i[sub][r] * alpha[sub][r] + L[r];
#pragma unroll
            for (int dc = 0; dc < 4; dc++)
#pragma unroll
                for (int r = 0; r < 4; r++) O[sub][dc][r] *= alpha[sub][r];
        }
#pragma unroll
        for (int s = 0; s < 2; s++)
#pragma unroll
            for (int dc = 0; dc < 4; dc++) {
                short8 vf = *(const short8*)(Vb + s * 2048 + (dc * 16 + ln) * 32 + quad * 8);
                O[0][dc] = __builtin_amdgcn_mfma_f32_16x16x32_bf16(pf[0][s], vf, O[0][dc], 0, 0, 0);
                O[1][dc] = __builtin_amdgcn_mfma_f32_16x16x32_bf16(pf[1][s], vf, O[1][dc], 0, 0, 0);
            }
    }
    // epilogue: o[b][t][h*64+d] = O/l
#pragma unroll
    for (int sub = 0; sub < 2; sub++)
#pragma unroll
        for (int r = 0; r < 4; r++) {
            float inv = 1.0f / l_i[sub][r];
            int t = t0 + w * 32 + sub * 16 + quad * 4 + r;
            ushort_t* orow = o + ((long)b * 2048 + t) * 1024 + h * 64;
#pragma unroll
            for (int dc = 0; dc < 4; dc++) orow[dc * 16 + ln] = f2bf(O[sub][dc][r] * inv);
        }
}

extern "C" void kernel_launch(void* const* d_in, const int* in_sizes, int n_in,
                              void* d_out, int out_size, void* d_ws, size_t ws_size,
                              hipStream_t stream) {
    const float* x   = (const float*)d_in[0];
    const float* Wq  = (const float*)d_in[1];
    const float* bq  = (const float*)d_in[2];
    const float* Wk  = (const float*)d_in[3];
    const float* bk  = (const float*)d_in[4];
    const float* Wv  = (const float*)d_in[5];
    const float* bv  = (const float*)d_in[6];
    const float* Wo  = (const float*)d_in[7];
    const float* bo  = (const float*)d_in[8];
    const float* g1  = (const float*)d_in[9];
    const float* be1 = (const float*)d_in[10];
    const float* g2  = (const float*)d_in[11];
    const float* be2 = (const float*)d_in[12];
    const float* W1  = (const float*)d_in[13];
    const float* b1  = (const float*)d_in[14];
    const float* W2  = (const float*)d_in[15];
    const float* b2  = (const float*)d_in[16];
    float* out = (float*)d_out;

    const long MB = 1 << 20;
    char* w = (char*)d_ws;
    ushort_t* xn  = (ushort_t*)(w);            // [8192,1024] bf16; reused as attn output o
    float*    x2  = (float*)(w + 16 * MB);     // [8192,1024] f32 (first 12KB doubles as biasCat)
    ushort_t* qb  = (ushort_t*)(w + 48 * MB);  // [B,T,C] bf16; kb,vtb contiguous after
    ushort_t* kb  = (ushort_t*)(w + 64 * MB);  // [B,T,C] bf16
    ushort_t* vtb = (ushort_t*)(w + 80 * MB);  // [B,H,DH,T] bf16
    ushort_t* xn2 = qb;                        // alias (qb dead after attention)
    ushort_t* h1  = (ushort_t*)(w + 64 * MB);  // [8192,2048] bf16 (kb/vtb dead)
    ushort_t* WqT = (ushort_t*)(w + 96 * MB);  // [H,DH,C]; WqT/WkT/WvT contiguous = QKV B^T
    ushort_t* WkT = (ushort_t*)(w + 98 * MB);
    ushort_t* WvT = (ushort_t*)(w + 100 * MB);
    ushort_t* WoT = (ushort_t*)(w + 102 * MB); // [C,C]^T
    ushort_t* W1T = (ushort_t*)(w + 104 * MB); // [DFF,C]
    ushort_t* W2T = (ushort_t*)(w + 112 * MB); // [C,DFF]  (ends at 120 MB)
    float* biasCat = x2;                       // 3072 floats, dead before Wo writes x2

    dim3 tb(32, 8);
    transpose_kernel<<<dim3(32, 2, 16), tb, 0, stream>>>(Wq, WqT, 1024, 64);
    transpose_kernel<<<dim3(32, 2, 16), tb, 0, stream>>>(Wk, WkT, 1024, 64);
    transpose_kernel<<<dim3(32, 2, 16), tb, 0, stream>>>(Wv, WvT, 1024, 64);
    transpose_kernel<<<dim3(32, 32, 1), tb, 0, stream>>>(Wo, WoT, 1024, 1024);
    transpose_kernel<<<dim3(32, 128, 1), tb, 0, stream>>>(W1, W1T, 1024, 4096);
    transpose_kernel<<<dim3(128, 32, 1), tb, 0, stream>>>(W2, W2T, 4096, 1024);
    concat_bias_kernel<<<12, 256, 0, stream>>>(bq, bk, bv, biasCat);

    ln_kernel<<<8192, 256, 0, stream>>>(x, xn, g1, be1);
    // fused QKV: q,k -> [2][B,T,C] at qb; v -> [B,H,DH,T] at vtb (= qb + 16M elems)
    gemm128_qkv_kernel<<<dim3(64, 24), 256, 0, stream>>>(xn, WqT, qb, biasCat);
    attn_kernel<<<1024, 256, 0, stream>>>(qb, kb, vtb, xn /* o */);
    // x2 = x + o @ Wo + bo   (fp32 out)
    gemm128_f32_kernel<<<dim3(64, 8), 256, 0, stream>>>(xn, 1024, WoT, 1024, 1024,
                                                        x2, 2048L * 1024, 1024, bo, x);
    ln_kernel<<<8192, 256, 0, stream>>>((const float*)x2, xn2, g2, be2);
    // FFN in two DFF=2048 halves (ws budget)
    gemm128_bf16_relu_kernel<<<dim3(64, 16), 256, 0, stream>>>(
        xn2, 1024, W1T, 1024, 1024, h1, 2048L * 2048, 2048, b1);
    gemm128_f32_kernel<<<dim3(64, 8), 256, 0, stream>>>(
        h1, 2048, W2T, 4096, 2048, out, 2048L * 1024, 1024, b2, x2);
    gemm128_bf16_relu_kernel<<<dim3(64, 16), 256, 0, stream>>>(
        xn2, 1024, W1T + 2048L * 1024, 1024, 1024, h1, 2048L * 2048, 2048, b1 + 2048);
    gemm128_f32_kernel<<<dim3(64, 8), 256, 0, stream>>>(
        h1, 2048, W2T + 2048, 4096, 2048, out, 2048L * 1024, 1024, nullptr, out);
}

// Round 6
// 639.956 us; speedup vs baseline: 12.1895x; 1.0979x over previous
//
#include <hip/hip_runtime.h>
#include <hip/hip_bf16.h>
#include <stdint.h>

typedef unsigned short ushort_t;
typedef short short8 __attribute__((ext_vector_type(8)));
typedef unsigned short ushortx8 __attribute__((ext_vector_type(8)));
typedef float floatx4 __attribute__((ext_vector_type(4)));

__device__ __forceinline__ float b2f(ushort_t u) {
    return __uint_as_float(((unsigned int)u) << 16);
}
__device__ __forceinline__ ushort_t f2bf(float f) {
    unsigned int u = __float_as_uint(f);
    unsigned int r = u + 0x7FFFu + ((u >> 16) & 1u);
    return (ushort_t)(r >> 16);
}
__device__ __forceinline__ unsigned int pack2bf(float a, float b) {
    return (unsigned int)f2bf(a) | ((unsigned int)f2bf(b) << 16);
}
// async global->LDS, 16B per lane; lds base wave-uniform, lanes land at base+lane*16
__device__ __forceinline__ void gll16(const void* g, void* l) {
    __builtin_amdgcn_global_load_lds((const __attribute__((address_space(1))) unsigned int*)g,
                                     (__attribute__((address_space(3))) unsigned int*)l,
                                     16, 0, 0);
}

// ---------------- transpose + downcast: out_bf16[n*K + k] = in_f32[k*N + n], batched ----
__global__ void transpose_kernel(const float* __restrict__ in, ushort_t* __restrict__ out,
                                 int K, int N) {
    __shared__ float tile[32][33];
    in += (long)blockIdx.z * K * N;
    out += (long)blockIdx.z * K * N;
    int k0 = blockIdx.x * 32, n0 = blockIdx.y * 32;
    int x = threadIdx.x, y = threadIdx.y;  // (32, 8)
#pragma unroll
    for (int i = 0; i < 4; i++)
        tile[y + 8 * i][x] = in[(long)(k0 + y + 8 * i) * N + n0 + x];
    __syncthreads();
#pragma unroll
    for (int i = 0; i < 4; i++)
        out[(long)(n0 + y + 8 * i) * K + k0 + x] = f2bf(tile[x][y + 8 * i]);
}

// concat bias for fused QKV
__global__ void concat_bias_kernel(const float* __restrict__ bq, const float* __restrict__ bk,
                                   const float* __restrict__ bv, float* __restrict__ dst) {
    int i = blockIdx.x * 256 + threadIdx.x;
    dst[i] = i < 1024 ? bq[i] : (i < 2048 ? bk[i - 1024] : bv[i - 2048]);
}

// ---------------- LayerNorm over C=1024, f32 in -> bf16 out ----------------
__global__ __launch_bounds__(256) void ln_kernel(const float* __restrict__ in,
                                                 ushort_t* __restrict__ out,
                                                 const float* __restrict__ g,
                                                 const float* __restrict__ b) {
    long row = blockIdx.x;
    int tid = threadIdx.x;
    float4 v4 = *((const float4*)(in + row * 1024) + tid);
    float v[4] = {v4.x, v4.y, v4.z, v4.w};
    float s1 = v[0] + v[1] + v[2] + v[3];
    float s2 = v[0] * v[0] + v[1] * v[1] + v[2] * v[2] + v[3] * v[3];
#pragma unroll
    for (int m = 32; m >= 1; m >>= 1) {
        s1 += __shfl_xor(s1, m);
        s2 += __shfl_xor(s2, m);
    }
    __shared__ float r1[4], r2[4];
    int w = tid >> 6;
    if ((tid & 63) == 0) { r1[w] = s1; r2[w] = s2; }
    __syncthreads();
    s1 = r1[0] + r1[1] + r1[2] + r1[3];
    s2 = r2[0] + r2[1] + r2[2] + r2[3];
    float mu = s1 * (1.0f / 1024.0f);
    float var = s2 * (1.0f / 1024.0f) - mu * mu;
    float inv = rsqrtf(var + 1e-5f);
    float y[4];
#pragma unroll
    for (int i = 0; i < 4; i++)
        y[i] = (v[i] - mu) * inv * g[tid * 4 + i] + b[tid * 4 + i];
    unsigned int lo = (unsigned int)f2bf(y[0]) | ((unsigned int)f2bf(y[1]) << 16);
    unsigned int hi = (unsigned int)f2bf(y[2]) | ((unsigned int)f2bf(y[3]) << 16);
    *(uint2*)(out + row * 1024 + tid * 4) = make_uint2(lo, hi);
}

// ------- 128x128 MFMA GEMM, bf16 A and B^T, double-buffered global_load_lds pipeline ----
// MODE 0: off = (m>>11)*cBatch + (m&2047)*ldc + n   (+bias/relu/resid)
// MODE 2 (QKV): n<1024 -> q [B,T,C]; n<2048 -> k (contig after q); n>=2048 -> v^T [B,H,DH,T]
template <typename OutT, int RELU, int MODE>
__device__ __forceinline__ void gemm128(
    const ushort_t* __restrict__ A, int lda,
    const ushort_t* __restrict__ Bt, int ldb, int K,
    OutT* __restrict__ C, long cBatch, int ldc,
    const float* __restrict__ bias, const float* __restrict__ resid,
    ushort_t* As, ushort_t* Bs) {   // each [2][128*32]
    int m0 = blockIdx.x * 128, n0 = blockIdx.y * 128;
    int tid = threadIdx.x, lane = tid & 63, w = tid >> 6;
    int ln = lane & 15, quad = lane >> 4;
    int wr = w >> 1, wc = w & 1;
    int lr = lane >> 2, lc = (lane & 3) * 8;

    auto stage = [&](int k0, int buf) {
#pragma unroll
        for (int i = 0; i < 4; i++) {
            int id = w * 4 + i;  // wave-uniform
            int blk = id & 7;
            int row = blk * 16 + lr;
            if (id < 8)
                gll16(A + (long)(m0 + row) * lda + k0 + lc, As + buf * 4096 + blk * 512);
            else
                gll16(Bt + (long)(n0 + row) * ldb + k0 + lc, Bs + buf * 4096 + blk * 512);
        }
    };

    floatx4 acc[4][4];
#pragma unroll
    for (int a = 0; a < 4; a++)
#pragma unroll
        for (int bb = 0; bb < 4; bb++) acc[a][bb] = floatx4{0, 0, 0, 0};

    stage(0, 0);
    int cur = 0;
    for (int k0 = 0; k0 < K; k0 += 32, cur ^= 1) {
        __syncthreads();  // own staged loads drained; other buffer free
        if (k0 + 32 < K) stage(k0 + 32, cur ^ 1);
        const ushort_t* Ab = As + cur * 4096;
        const ushort_t* Bb = Bs + cur * 4096;
        short8 af[4], bf[4];
#pragma unroll
        for (int j = 0; j < 4; j++) {
            af[j] = *(const short8*)(Ab + (wr * 64 + j * 16 + ln) * 32 + quad * 8);
            bf[j] = *(const short8*)(Bb + (wc * 64 + j * 16 + ln) * 32 + quad * 8);
        }
#pragma unroll
        for (int a = 0; a < 4; a++)
#pragma unroll
            for (int bb = 0; bb < 4; bb++)
                acc[a][bb] = __builtin_amdgcn_mfma_f32_16x16x32_bf16(af[a], bf[bb], acc[a][bb], 0, 0, 0);
    }
#pragma unroll
    for (int bb = 0; bb < 4; bb++) {
        int gn = n0 + wc * 64 + bb * 16 + ln;
        float bv = bias ? bias[gn] : 0.0f;
#pragma unroll
        for (int a = 0; a < 4; a++) {
#pragma unroll
            for (int r = 0; r < 4; r++) {
                int gm = m0 + wr * 64 + a * 16 + quad * 4 + r;
                float val = acc[a][bb][r] + bv;
                if (RELU) val = fmaxf(val, 0.0f);
                if constexpr (MODE == 2) {
                    int gnl = gn & 1023;
                    long off;
                    if (gn < 2048)  // q or k: [2][B,T,1024] contiguous
                        off = (long)(gn >> 10) * 8388608 + (long)(gm >> 11) * 2097152 +
                              (long)(gm & 2047) * 1024 + gnl;
                    else  // v transposed: [B,H,64,2048] at +16M elems
                        off = 16777216L +
                              ((((long)(gm >> 11)) * 16 + (gnl >> 6)) * 64 + (gnl & 63)) * 2048 +
                              (gm & 2047);
                    C[off] = (OutT)f2bf(val);
                } else {
                    long off = (long)(gm >> 11) * cBatch + (long)(gm & 2047) * ldc + gn;
                    if (resid) val += resid[off];
                    if constexpr (sizeof(OutT) == 2)
                        C[off] = (OutT)f2bf(val);
                    else
                        C[off] = (OutT)val;
                }
            }
        }
    }
}

__global__ __launch_bounds__(256) void gemm128_qkv_kernel(
    const ushort_t* __restrict__ A, const ushort_t* __restrict__ Bt,
    ushort_t* __restrict__ C, const float* __restrict__ bias) {
    __shared__ ushort_t As[2 * 128 * 32];
    __shared__ ushort_t Bs[2 * 128 * 32];
    gemm128<ushort_t, 0, 2>(A, 1024, Bt, 1024, 1024, C, 0, 0, bias, nullptr, As, Bs);
}

__global__ __launch_bounds__(256) void gemm128_bf16_relu_kernel(
    const ushort_t* __restrict__ A, int lda, const ushort_t* __restrict__ Bt, int ldb, int K,
    ushort_t* __restrict__ C, long cBatch, int ldc, const float* __restrict__ bias) {
    __shared__ ushort_t As[2 * 128 * 32];
    __shared__ ushort_t Bs[2 * 128 * 32];
    gemm128<ushort_t, 1, 0>(A, lda, Bt, ldb, K, C, cBatch, ldc, bias, nullptr, As, Bs);
}

__global__ __launch_bounds__(256) void gemm128_f32_kernel(
    const ushort_t* __restrict__ A, int lda, const ushort_t* __restrict__ Bt, int ldb, int K,
    float* __restrict__ C, long cBatch, int ldc,
    const float* __restrict__ bias, const float* __restrict__ resid) {
    __shared__ ushort_t As[2 * 128 * 32];
    __shared__ ushort_t Bs[2 * 128 * 32];
    gemm128<float, 0, 0>(A, lda, Bt, ldb, K, C, cBatch, ldc, bias, resid, As, Bs);
}

// ---------------- MFMA flash attention v4: S^T formulation, 512 threads ----------------
// q,k: [B,T,1024] bf16 (head h at cols h*64..); vt: [B,H,64,2048] bf16; o: [B,T,1024] bf16
// 512 blocks (XCD-swizzled), 8 waves, wave owns 32 q rows (2 subtiles of 16).
// S^T = K.Q^T so softmax stats are per-lane (q = ln); P staged [q][kv] via b64 writes.
#define PSTR 72
__global__ __launch_bounds__(512, 4) void attn_kernel(
    const ushort_t* __restrict__ q, const ushort_t* __restrict__ k,
    const ushort_t* __restrict__ vt, ushort_t* __restrict__ o) {
    __shared__ ushort_t Klds[2 * 4096];        // [buf][s-half][kv row 64][32]
    __shared__ ushort_t Vlds[2 * 4096];        // [buf][kv-half][d row 64][32]
    __shared__ ushort_t Plds[8 * 32 * PSTR];   // per-wave, per-sub 16 q rows x 64 kv
    int flat = blockIdx.x;
    // XCD swizzle: the 8 q-tiles of one (b,h) share flat%8 -> same XCD L2
    int bh = (flat & 7) * 8 + (flat >> 6);
    int xt = (flat >> 3) & 7;
    int b = bh >> 4, h = bh & 15;
    int t0 = xt * 256;
    int tid = threadIdx.x, lane = tid & 63, w = tid >> 6;
    int ln = lane & 15, quad = lane >> 4;
    int lr = lane >> 2, lc = (lane & 3) * 8;
    int bsrc = (lane & 48) + ((lane >> 4) << 2);  // broadcast src: ln' = quad*4+r

    // Q fragments (B-operand for S^T), x8 (= sqrt(DH)) folded in (exact in bf16)
    const ushort_t* qbase = q + ((long)b * 2048 + t0 + w * 32) * 1024 + h * 64;
    short8 qf[2][2];
#pragma unroll
    for (int sub = 0; sub < 2; sub++)
#pragma unroll
        for (int s = 0; s < 2; s++) {
            ushortx8 t = *(const ushortx8*)(qbase + (long)(sub * 16 + ln) * 1024 + s * 32 + quad * 8);
#pragma unroll
            for (int j = 0; j < 8; j++) qf[sub][s][j] = (short)f2bf(b2f(t[j]) * 8.0f);
        }

    floatx4 O[2][4];
    float m_i[2] = {-1e30f, -1e30f}, l_i[2] = {0.0f, 0.0f};  // per-lane: q = ln (per sub)
#pragma unroll
    for (int sub = 0; sub < 2; sub++)
#pragma unroll
        for (int i = 0; i < 4; i++) O[sub][i] = floatx4{0, 0, 0, 0};

    ushort_t* Pw = Plds + w * 32 * PSTR;
    long krow0 = (long)b * 2048 * 1024 + h * 64;
    const ushort_t* vbase = vt + (long)bh * 64 * 2048;

    auto stage = [&](int kv0, int buf) {
#pragma unroll
        for (int i = 0; i < 2; i++) {
            int id = w * 2 + i;  // 0..15: 8 K-quarters then 8 V-quarters
            int s = (id >> 2) & 1, qt = id & 3;
            int row = qt * 16 + lr;
            if (id < 8)
                gll16(k + krow0 + (long)(kv0 + row) * 1024 + s * 32 + lc,
                      Klds + buf * 4096 + s * 2048 + qt * 512);
            else
                gll16(vbase + (long)row * 2048 + kv0 + s * 32 + lc,
                      Vlds + buf * 4096 + s * 2048 + qt * 512);
        }
    };

    stage(0, 0);
    int cur = 0;
    for (int t32 = 0; t32 < 32; t32++, cur ^= 1) {
        __syncthreads();  // own staged loads drained -> this buffer ready; other free
        if (t32 < 31) stage((t32 + 1) * 64, cur ^ 1);
        const ushort_t* Kb = Klds + cur * 4096;
        const ushort_t* Vb = Vlds + cur * 4096;

        float alpha[2];
#pragma unroll
        for (int sub = 0; sub < 2; sub++) {
            // Z = S^T tile: mfma(A=K, B=Q^T) -> Z[kv = nc*16+quad*4+r][q = ln]
            floatx4 Z[4];
#pragma unroll
            for (int nc = 0; nc < 4; nc++) Z[nc] = floatx4{0, 0, 0, 0};
#pragma unroll
            for (int s = 0; s < 2; s++)
#pragma unroll
                for (int nc = 0; nc < 4; nc++) {
                    short8 kf = *(const short8*)(Kb + s * 2048 + (nc * 16 + ln) * 32 + quad * 8);
                    Z[nc] = __builtin_amdgcn_mfma_f32_16x16x32_bf16(kf, qf[sub][s], Z[nc], 0, 0, 0);
                }
            // per-lane stats over 16 in-lane values + 2 cross-quad hops
            float mx = -1e30f;
#pragma unroll
            for (int nc = 0; nc < 4; nc++)
#pragma unroll
                for (int r = 0; r < 4; r++) mx = fmaxf(mx, Z[nc][r]);
            mx = fmaxf(mx, __shfl_xor(mx, 16));
            mx = fmaxf(mx, __shfl_xor(mx, 32));
            float nm = fmaxf(m_i[sub], mx);
            alpha[sub] = __expf(m_i[sub] - nm);
            m_i[sub] = nm;
            float rs = 0.0f;
            ushort_t* Ps = Pw + sub * 16 * PSTR + ln * PSTR;
#pragma unroll
            for (int nc = 0; nc < 4; nc++) {
                float p0 = __expf(Z[nc][0] - nm), p1 = __expf(Z[nc][1] - nm);
                float p2 = __expf(Z[nc][2] - nm), p3 = __expf(Z[nc][3] - nm);
                rs += (p0 + p1) + (p2 + p3);
                *(uint2*)(Ps + nc * 16 + quad * 4) = make_uint2(pack2bf(p0, p1), pack2bf(p2, p3));
            }
            rs += __shfl_xor(rs, 16);
            rs += __shfl_xor(rs, 32);
            l_i[sub] = l_i[sub] * alpha[sub] + rs;
        }
        // O rescale (alpha broadcast from stat space to row space) + PV
#pragma unroll
        for (int sub = 0; sub < 2; sub++) {
#pragma unroll
            for (int r = 0; r < 4; r++) {
                float ar = __shfl(alpha[sub], bsrc + r);
#pragma unroll
                for (int dc = 0; dc < 4; dc++) O[sub][dc][r] *= ar;
            }
            short8 pf[2];
#pragma unroll
            for (int s = 0; s < 2; s++)
                pf[s] = *(const short8*)(Pw + (sub * 16 + ln) * PSTR + s * 32 + quad * 8);
#pragma unroll
            for (int s = 0; s < 2; s++)
#pragma unroll
                for (int dc = 0; dc < 4; dc++) {
                    short8 vf = *(const short8*)(Vb + s * 2048 + (dc * 16 + ln) * 32 + quad * 8);
                    O[sub][dc] = __builtin_amdgcn_mfma_f32_16x16x32_bf16(pf[s], vf, O[sub][dc], 0, 0, 0);
                }
        }
    }
    // epilogue: o[b][t][h*64+d] = O/l   (l broadcast stat->row space)
#pragma unroll
    for (int sub = 0; sub < 2; sub++)
#pragma unroll
        for (int r = 0; r < 4; r++) {
            float inv = 1.0f / __shfl(l_i[sub], bsrc + r);
            int t = t0 + w * 32 + sub * 16 + quad * 4 + r;
            ushort_t* orow = o + ((long)b * 2048 + t) * 1024 + h * 64;
#pragma unroll
            for (int dc = 0; dc < 4; dc++) orow[dc * 16 + ln] = f2bf(O[sub][dc][r] * inv);
        }
}

extern "C" void kernel_launch(void* const* d_in, const int* in_sizes, int n_in,
                              void* d_out, int out_size, void* d_ws, size_t ws_size,
                              hipStream_t stream) {
    const float* x   = (const float*)d_in[0];
    const float* Wq  = (const float*)d_in[1];
    const float* bq  = (const float*)d_in[2];
    const float* Wk  = (const float*)d_in[3];
    const float* bk  = (const float*)d_in[4];
    const float* Wv  = (const float*)d_in[5];
    const float* bv  = (const float*)d_in[6];
    const float* Wo  = (const float*)d_in[7];
    const float* bo  = (const float*)d_in[8];
    const float* g1  = (const float*)d_in[9];
    const float* be1 = (const float*)d_in[10];
    const float* g2  = (const float*)d_in[11];
    const float* be2 = (const float*)d_in[12];
    const float* W1  = (const float*)d_in[13];
    const float* b1  = (const float*)d_in[14];
    const float* W2  = (const float*)d_in[15];
    const float* b2  = (const float*)d_in[16];
    float* out = (float*)d_out;

    const long MB = 1 << 20;
    char* w = (char*)d_ws;
    ushort_t* xn  = (ushort_t*)(w);            // [8192,1024] bf16; reused as attn output o
    float*    x2  = (float*)(w + 16 * MB);     // [8192,1024] f32 (first 12KB doubles as biasCat)
    ushort_t* qb  = (ushort_t*)(w + 48 * MB);  // [B,T,C] bf16; kb,vtb contiguous after
    ushort_t* kb  = (ushort_t*)(w + 64 * MB);  // [B,T,C] bf16
    ushort_t* vtb = (ushort_t*)(w + 80 * MB);  // [B,H,DH,T] bf16
    ushort_t* xn2 = qb;                        // alias (qb dead after attention)
    ushort_t* h1  = (ushort_t*)(w + 64 * MB);  // [8192,2048] bf16 (kb/vtb dead)
    ushort_t* WqT = (ushort_t*)(w + 96 * MB);  // [H,DH,C]; WqT/WkT/WvT contiguous = QKV B^T
    ushort_t* WkT = (ushort_t*)(w + 98 * MB);
    ushort_t* WvT = (ushort_t*)(w + 100 * MB);
    ushort_t* WoT = (ushort_t*)(w + 102 * MB); // [C,C]^T
    ushort_t* W1T = (ushort_t*)(w + 104 * MB); // [DFF,C]
    ushort_t* W2T = (ushort_t*)(w + 112 * MB); // [C,DFF]  (ends at 120 MB)
    float* biasCat = x2;                       // 3072 floats, dead before Wo writes x2

    dim3 tb(32, 8);
    transpose_kernel<<<dim3(32, 2, 16), tb, 0, stream>>>(Wq, WqT, 1024, 64);
    transpose_kernel<<<dim3(32, 2, 16), tb, 0, stream>>>(Wk, WkT, 1024, 64);
    transpose_kernel<<<dim3(32, 2, 16), tb, 0, stream>>>(Wv, WvT, 1024, 64);
    transpose_kernel<<<dim3(32, 32, 1), tb, 0, stream>>>(Wo, WoT, 1024, 1024);
    transpose_kernel<<<dim3(32, 128, 1), tb, 0, stream>>>(W1, W1T, 1024, 4096);
    transpose_kernel<<<dim3(128, 32, 1), tb, 0, stream>>>(W2, W2T, 4096, 1024);
    concat_bias_kernel<<<12, 256, 0, stream>>>(bq, bk, bv, biasCat);

    ln_kernel<<<8192, 256, 0, stream>>>(x, xn, g1, be1);
    // fused QKV: q,k -> [2][B,T,C] at qb; v -> [B,H,DH,T] at vtb (= qb + 16M elems)
    gemm128_qkv_kernel<<<dim3(64, 24), 256, 0, stream>>>(xn, WqT, qb, biasCat);
    attn_kernel<<<512, 512, 0, stream>>>(qb, kb, vtb, xn /* o */);
    // x2 = x + o @ Wo + bo   (fp32 out)
    gemm128_f32_kernel<<<dim3(64, 8), 256, 0, stream>>>(xn, 1024, WoT, 1024, 1024,
                                                        x2, 2048L * 1024, 1024, bo, x);
    ln_kernel<<<8192, 256, 0, stream>>>((const float*)x2, xn2, g2, be2);
    // FFN in two DFF=2048 halves (ws budget)
    gemm128_bf16_relu_kernel<<<dim3(64, 16), 256, 0, stream>>>(
        xn2, 1024, W1T, 1024, 1024, h1, 2048L * 2048, 2048, b1);
    gemm128_f32_kernel<<<dim3(64, 8), 256, 0, stream>>>(
        h1, 2048, W2T, 4096, 2048, out, 2048L * 1024, 1024, b2, x2);
    gemm128_bf16_relu_kernel<<<dim3(64, 16), 256, 0, stream>>>(
        xn2, 1024, W1T + 2048L * 1024, 1024, 1024, h1, 2048L * 2048, 2048, b1 + 2048);
    gemm128_f32_kernel<<<dim3(64, 8), 256, 0, stream>>>(
        h1, 2048, W2T + 2048, 4096, 2048, out, 2048L * 1024, 1024, nullptr, out);
}